// Round 7
// baseline (576.726 us; speedup 1.0000x reference)
//
#include <hip/hip_runtime.h>
#include <hip/hip_bf16.h>
#include <cstdint>

typedef __bf16 bf16;
typedef __bf16 bf16x8 __attribute__((ext_vector_type(8)));
typedef float f32x4 __attribute__((ext_vector_type(4)));
typedef unsigned int u32;

#define E_TOT   262144
#define NNODE   512
#define NDIM    128
#define EDIM    64
#define GDIM    32
#define FIN     320
#define H1D     256
#define OUTD    64
#define AHD     64
#define NHEADS  4
#define NSEG    4096
#define NND     4096   // total nodes (8*512)
#define TE      48
#define CAP     192    // bucket capacity; counts ~Poisson(64), P(>=192) < 1e-50

#define SX_STR  72     // 144B stride: %32 words = 4 -> 2-way (free)
#define SH_STR  264    // 528B stride: %32 words = 4 -> 2-way

// fp32 params block layout (floats) -- only B2/A2/AB2 used by k_edge now
#define PRM_LNG 0
#define PRM_LNB 320
#define PRM_B1  640
#define PRM_B2  896
#define PRM_A2  960
#define PRM_AB1 1216
#define PRM_AB2 1280
#define PRM_TOT 1284

// LDS layout (bytes). sH 48x264x2=25344; sX/sA share [25600,32512) (sX dead
// after GEMM1 barrier, sA written phase 3). sMu float2[48]; sA2 f32[256]; idx.
#define SMEM_SH    0
#define SMEM_SX    25600
#define SMEM_MU    32512
#define SMEM_A2    32896
#define SMEM_IDX   33920   // sBi[48], sNs[48], sNr[48]
#define SMEM_TOT   34496   // x4 = 137984 <= 160K -> 4 blocks/CU

// k_prep block sections
#define KP_W1E   0      // 64:  W1eT [256][64] bf16, gamma-folded
#define KP_A1E   64     // 16:  A1eT [64][64]  bf16, gamma-folded
#define KP_W2T   80     // 64:  W2T  [64][256] bf16
#define KP_PRM   144    // 6:   params copy
#define KP_GL    150    // 8:   per-graph glob tables
#define KP_GC    158    // 1:   Gvec/Cvec (256)
#define KP_GCA   159    // 1:   GAv/CAv (64)
#define KP_TAB   160    // 512: node tables (8 nodes/block): Stab/Rtab/SA/RA/SQ
#define KP_SCAT  672    // 1024: bucket scatter
#define KP_NBLK  1696

__device__ __forceinline__ float siluf(float v) {
    return v / (1.0f + __expf(-v));
}

__device__ __forceinline__ float ldf(const void* p, size_t i, bool isb) {
    return isb ? (float)((const bf16*)p)[i] : ((const float*)p)[i];
}

// Per-wave dtype probe: 1=bf16 data, 0=fp32 data. Reads first 256 u16 of nodes.
__device__ __forceinline__ bool probe_bf16(const void* nodes, int t) {
    const unsigned short* u16 = (const unsigned short*)nodes;
    int lane = t & 63;
    int pl = 0;
    #pragma unroll
    for (int i = 0; i < 4; i++) {
        unsigned short u = u16[lane * 4 + i];
        int expo = (u >> 7) & 0xFF;
        pl += (((u & 0x7FFF) == 0) || (expo >= 97 && expo <= 137)) ? 1 : 0;
    }
    #pragma unroll
    for (int m = 1; m < 64; m <<= 1) pl += __shfl_xor(pl, m);
    return pl >= 240;
}

// ---------------- K_prep: weights + LN-decomposition tables + scatter ----------------
// Decomposition: LN(x)∘gamma+beta through W1 ==
//   rstd*[(x∘g)W] - rstd*mu*Gvec + Cvec, with (x∘g)W split into
//   edges0-part (per-edge GEMM, K=64, gamma in W1eT), send/recv node tables
//   (Stab/Rtab, f32), glob tables (raw, no LN), and mu/rstd from per-node
//   (sum,sumsq) pairs (SQ).
__global__ __launch_bounds__(256) void k_prep(
    const void* __restrict__ nodes, const void* __restrict__ globs,
    const void* __restrict__ W1, const void* __restrict__ W2, const void* __restrict__ A1,
    const void* __restrict__ ln_g, const void* __restrict__ ln_b,
    const void* __restrict__ b1, const void* __restrict__ b2,
    const void* __restrict__ A2, const void* __restrict__ ab1, const void* __restrict__ ab2,
    const int* __restrict__ bidx, const int* __restrict__ ridx,
    bf16* __restrict__ W1eT, bf16* __restrict__ A1eT, bf16* __restrict__ W2T,
    float* __restrict__ prm,
    float* __restrict__ Gvec, float* __restrict__ Cvec,
    float* __restrict__ GAv,  float* __restrict__ CAv,
    float* __restrict__ Gltab, float* __restrict__ GlAtab,
    float2* __restrict__ SQ,
    float* __restrict__ Stab, float* __restrict__ Rtab,
    float* __restrict__ SAtab, float* __restrict__ RAtab,
    u32* __restrict__ cnt, u32* __restrict__ order) {

    __shared__ float sNd[1024];   // 8 node rows (TAB section only)
    int b = blockIdx.x, t = threadIdx.x;

    if (b >= KP_SCAT) {                              // bucket scatter (cnt pre-zeroed)
        int ge = (b - KP_SCAT) * 256 + t;
        int seg = bidx[ge] * NNODE + ridx[ge];
        u32 pos = atomicAdd(&cnt[seg], 1u);
        if (pos < CAP) order[(size_t)seg * CAP + pos] = (u32)ge;
        return;
    }
    bool isb = probe_bf16(nodes, t);

    if (b < KP_A1E) {                                // W1eT[n][k] = g[k]*W1[k][n], k<64
        int i = b * 256 + t;                         // i < 16384
        int n = i >> 6, k = i & 63;
        W1eT[i] = (bf16)(ldf(ln_g, k, isb) * ldf(W1, (size_t)k * H1D + n, isb));
    } else if (b < KP_W2T) {                         // A1eT[n][k] = g[k]*A1[k][n], k<64
        int i = (b - KP_A1E) * 256 + t;              // i < 4096
        int n = i >> 6, k = i & 63;
        A1eT[i] = (bf16)(ldf(ln_g, k, isb) * ldf(A1, (size_t)k * AHD + n, isb));
    } else if (b < KP_PRM) {                         // W2 [256][64] -> W2T [64][256]
        int i = (b - KP_W2T) * 256 + t;
        int k = i >> 6, n = i & 63;
        W2T[n * H1D + k] = (bf16)ldf(W2, i, isb);
    } else if (b < KP_GL) {                          // params copy
        int i = (b - KP_PRM) * 256 + t;
        if (i < PRM_TOT) {
            const void* src; int off;
            if (i < 320)       { src = ln_g; off = i; }
            else if (i < 640)  { src = ln_b; off = i - 320; }
            else if (i < 896)  { src = b1;   off = i - 640; }
            else if (i < 960)  { src = b2;   off = i - 896; }
            else if (i < 1216) { src = A2;   off = i - 960; }
            else if (i < 1280) { src = ab1;  off = i - 1216; }
            else               { src = ab2;  off = i - 1280; }
            prm[i] = ldf(src, off, isb);
        }
    } else if (b < KP_GC) {                          // glob tables (raw, not LN'd)
        int bg = b - KP_GL;
        float acc = 0.f;
        #pragma unroll 4
        for (int k = 0; k < GDIM; k++)
            acc += ldf(globs, bg * GDIM + k, isb) * ldf(W1, (size_t)(FIN + k) * H1D + t, isb);
        Gltab[bg * H1D + t] = acc;
        if (t < AHD) {
            float a2 = 0.f;
            #pragma unroll 4
            for (int k = 0; k < GDIM; k++)
                a2 += ldf(globs, bg * GDIM + k, isb) * ldf(A1, (size_t)(FIN + k) * AHD + t, isb);
            GlAtab[bg * AHD + t] = a2;
        }
    } else if (b < KP_GCA) {                         // Gvec = g^T W1 ; Cvec = b1 + beta^T W1
        float g = 0.f, c = ldf(b1, t, isb);
        #pragma unroll 4
        for (int k = 0; k < FIN; k++) {
            float wv = ldf(W1, (size_t)k * H1D + t, isb);
            g += ldf(ln_g, k, isb) * wv;
            c += ldf(ln_b, k, isb) * wv;
        }
        Gvec[t] = g; Cvec[t] = c;
    } else if (b < KP_TAB) {                         // GAv/CAv over A1
        if (t < AHD) {
            float g = 0.f, c = ldf(ab1, t, isb);
            #pragma unroll 4
            for (int k = 0; k < FIN; k++) {
                float wv = ldf(A1, (size_t)k * AHD + t, isb);
                g += ldf(ln_g, k, isb) * wv;
                c += ldf(ln_b, k, isb) * wv;
            }
            GAv[t] = g; CAv[t] = c;
        }
    } else {                                         // node tables: 8 nodes/block
        int v0 = (b - KP_TAB) * 8;
        #pragma unroll
        for (int q = 0; q < 4; q++)
            sNd[t + q * 256] = ldf(nodes, (size_t)v0 * NDIM + t + q * 256, isb);
        __syncthreads();
        // SQ: per-node raw sum & sumsq (32 threads/node)
        {
            int nj = t >> 5, li = t & 31;
            float s = 0.f, qq = 0.f;
            #pragma unroll
            for (int m = 0; m < 4; m++) {
                float x = sNd[nj * NDIM + li + m * 32];
                s += x; qq += x * x;
            }
            #pragma unroll
            for (int m = 1; m < 32; m <<= 1) { s += __shfl_xor(s, m); qq += __shfl_xor(qq, m); }
            if (li == 0) SQ[v0 + nj] = make_float2(s, qq);
        }
        // Stab/Rtab: t = output col n
        {
            float aS[8] = {}, aR[8] = {};
            for (int k = 0; k < NDIM; k++) {
                float wS = ldf(ln_g, EDIM + k, isb) * ldf(W1, (size_t)(EDIM + k) * H1D + t, isb);
                float wR = ldf(ln_g, EDIM + NDIM + k, isb) * ldf(W1, (size_t)(EDIM + NDIM + k) * H1D + t, isb);
                #pragma unroll
                for (int j = 0; j < 8; j++) {
                    aS[j] += sNd[j * NDIM + k] * wS;
                    aR[j] += sNd[j * NDIM + k] * wR;
                }
            }
            #pragma unroll
            for (int j = 0; j < 8; j++) {
                Stab[(size_t)(v0 + j) * H1D + t] = aS[j];
                Rtab[(size_t)(v0 + j) * H1D + t] = aR[j];
            }
        }
        // SA/RA tables (64-wide): t < 64
        if (t < AHD) {
            float aS[8] = {}, aR[8] = {};
            for (int k = 0; k < NDIM; k++) {
                float wS = ldf(ln_g, EDIM + k, isb) * ldf(A1, (size_t)(EDIM + k) * AHD + t, isb);
                float wR = ldf(ln_g, EDIM + NDIM + k, isb) * ldf(A1, (size_t)(EDIM + NDIM + k) * AHD + t, isb);
                #pragma unroll
                for (int j = 0; j < 8; j++) {
                    aS[j] += sNd[j * NDIM + k] * wS;
                    aR[j] += sNd[j * NDIM + k] * wR;
                }
            }
            #pragma unroll
            for (int j = 0; j < 8; j++) {
                SAtab[(size_t)(v0 + j) * AHD + t] = aS[j];
                RAtab[(size_t)(v0 + j) * AHD + t] = aR[j];
            }
        }
    }
}

// ---------------- K1: fused per-edge-tile kernel (decomposed LN+GEMM1) ----------------
__global__ __launch_bounds__(256, 4) void k_edge(
    const void* __restrict__ nodes, const void* __restrict__ edges0,
    const float* __restrict__ prm,
    const int* __restrict__ bidx, const int* __restrict__ sidx,
    const int* __restrict__ ridx,
    const bf16* __restrict__ W1eT, const bf16* __restrict__ A1eT,
    const bf16* __restrict__ W2T,
    const float* __restrict__ Gvec, const float* __restrict__ Cvec,
    const float* __restrict__ GAv,  const float* __restrict__ CAv,
    const float* __restrict__ Gltab, const float* __restrict__ GlAtab,
    const float2* __restrict__ SQ,
    const float* __restrict__ Stab, const float* __restrict__ Rtab,
    const float* __restrict__ SAtab, const float* __restrict__ RAtab,
    void* __restrict__ outNE, float* __restrict__ scrS) {

    __shared__ __align__(16) char smem[SMEM_TOT];
    bf16*   sH   = (bf16*)(smem + SMEM_SH);
    bf16*   sX   = (bf16*)(smem + SMEM_SX);     // sA overlays sX after GEMM1
    bf16*   sA   = (bf16*)(smem + SMEM_SX);
    float2* sMu  = (float2*)(smem + SMEM_MU);   // phase0: node sums; phase1+: {mu,rstd}
    float*  sA2  = (float*)(smem + SMEM_A2);
    int*    sBi  = (int*)(smem + SMEM_IDX);
    int*    sNs  = sBi + TE;
    int*    sNr  = sBi + 2 * TE;

    const int t  = threadIdx.x;
    const int e0 = blockIdx.x * TE;
    const int ne = min(TE, E_TOT - e0);          // tail block: 16
    const bool isb = probe_bf16(nodes, t);

    // Phase 0: stage indices + node (sum,sumsq) pairs + A2
    if (t < TE) {
        int ge = e0 + t;
        int bi = 0, si = 0, ri = 0;
        if (t < ne) { bi = bidx[ge]; si = sidx[ge]; ri = ridx[ge]; }
        int ns = bi * NNODE + si, nr = bi * NNODE + ri;
        sBi[t] = bi; sNs[t] = ns; sNr[t] = nr;
        float2 a = SQ[ns], c = SQ[nr];
        sMu[t] = make_float2(a.x + c.x, a.y + c.y);
    } else if (t >= 64 && t < 128) {
        ((float4*)sA2)[t - 64] = ((const float4*)(prm + PRM_A2))[t - 64];
    }
    __syncthreads();

    // Phase 1 (lean): edges0 -> sX (raw bf16; gamma lives in W1eT/A1eT) + LN stats
    {
        const int eh = t >> 3, gl = t & 7;
        for (int half = 0; half < 2; half++) {
            const int e = half * 32 + eh;
            if (e >= TE) break;
            if (e >= ne) {
                bf16x8 zz = {};
                *(bf16x8*)&sX[e * SX_STR + gl * 8] = zz;
                if (gl == 0) sMu[e] = make_float2(0.f, 1.f);
                continue;
            }
            const size_t off = (size_t)(e0 + e) * EDIM + gl * 8;
            float v[8];
            bf16x8 o;
            if (isb) {
                o = *(const bf16x8*)((const bf16*)edges0 + off);
                #pragma unroll
                for (int ii = 0; ii < 8; ii++) v[ii] = (float)o[ii];
            } else {
                const float* sf = (const float*)edges0 + off;
                float4 f0 = ((const float4*)sf)[0];
                float4 f1 = ((const float4*)sf)[1];
                v[0]=f0.x; v[1]=f0.y; v[2]=f0.z; v[3]=f0.w;
                v[4]=f1.x; v[5]=f1.y; v[6]=f1.z; v[7]=f1.w;
                #pragma unroll
                for (int ii = 0; ii < 8; ii++) o[ii] = (bf16)v[ii];
            }
            *(bf16x8*)&sX[e * SX_STR + gl * 8] = o;
            float s = 0.f, sq = 0.f;
            #pragma unroll
            for (int ii = 0; ii < 8; ii++) { s += v[ii]; sq += v[ii] * v[ii]; }
            #pragma unroll
            for (int m = 1; m < 8; m <<= 1) { s += __shfl_xor(s, m); sq += __shfl_xor(sq, m); }
            if (gl == 0) {
                float2 nq = sMu[e];
                float st = s + nq.x, qt = sq + nq.y;
                float mean = st * (1.0f / FIN);
                float var  = qt * (1.0f / FIN) - mean * mean;
                sMu[e] = make_float2(mean, rsqrtf(var + 1e-5f));
            }
        }
    }
    __syncthreads();

    const int w = t >> 6, lane = t & 63, quad = lane >> 4, l15 = lane & 15;
    f32x4 z = {0.f, 0.f, 0.f, 0.f};

    // Phase 2: small GEMM1: edges0(48x64) @ W1eT(->256) + @ A1eT(->64), K=64
    f32x4 acc[3][4], accA[3];
    #pragma unroll
    for (int s2 = 0; s2 < 3; s2++) { accA[s2] = z; for (int i = 0; i < 4; i++) acc[s2][i] = z; }
    {
        const bf16* pW = W1eT + (size_t)(w * 64 + l15) * EDIM + quad * 8;
        const bf16* pA = A1eT + (size_t)(w * 16 + l15) * EDIM + quad * 8;
        #pragma unroll
        for (int kk = 0; kk < 2; kk++) {
            bf16x8 bw[4], ba;
            #pragma unroll
            for (int i = 0; i < 4; i++) bw[i] = *(const bf16x8*)(pW + i * 16 * EDIM + kk * 32);
            ba = *(const bf16x8*)(pA + kk * 32);
            const int kc = kk * 32 + quad * 8;
            bf16x8 a[3];
            #pragma unroll
            for (int s2 = 0; s2 < 3; s2++) a[s2] = *(bf16x8*)&sX[(s2 * 16 + l15) * SX_STR + kc];
            #pragma unroll
            for (int i = 0; i < 4; i++)
                #pragma unroll
                for (int s2 = 0; s2 < 3; s2++)
                    acc[s2][i] = __builtin_amdgcn_mfma_f32_16x16x32_bf16(a[s2], bw[i], acc[s2][i], 0, 0, 0);
            #pragma unroll
            for (int s2 = 0; s2 < 3; s2++)
                accA[s2] = __builtin_amdgcn_mfma_f32_16x16x32_bf16(a[s2], ba, accA[s2], 0, 0, 0);
        }
    }
    __syncthreads();   // sX dead; sA overlays it

    // Phase 3: decomposed epilogue: val = rstd*(acc + S + R - mu*G) + Gl + C
    #pragma unroll 1
    for (int i = 0; i < 4; i++) {
        const int n = w * 64 + i * 16 + l15;
        const float Gn = Gvec[n], Cn = Cvec[n];
        #pragma unroll
        for (int s2 = 0; s2 < 3; s2++)
            #pragma unroll
            for (int r = 0; r < 4; r++) {
                const int row = s2 * 16 + quad * 4 + r;
                float2 mr = sMu[row];
                float S = Stab[(size_t)sNs[row] * H1D + n] + Rtab[(size_t)sNr[row] * H1D + n];
                float val = mr.y * (acc[s2][i][r] + S - mr.x * Gn) + Gltab[sBi[row] * H1D + n] + Cn;
                sH[row * SH_STR + n] = (bf16)siluf(val);
            }
    }
    {
        const int n = w * 16 + l15;
        const float Gn = GAv[n], Cn = CAv[n];
        #pragma unroll
        for (int s2 = 0; s2 < 3; s2++)
            #pragma unroll
            for (int r = 0; r < 4; r++) {
                const int row = s2 * 16 + quad * 4 + r;
                float2 mr = sMu[row];
                float S = SAtab[(size_t)sNs[row] * AHD + n] + RAtab[(size_t)sNr[row] * AHD + n];
                float val = mr.y * (accA[s2][r] + S - mr.x * Gn) + GlAtab[sBi[row] * AHD + n] + Cn;
                sA[row * SX_STR + n] = (bf16)siluf(val);
            }
    }
    __syncthreads();

    // Phase 4: scores -> plain global stream (no atomics)
    if (t < TE * NHEADS) {
        const int e = t >> 2, h = t & 3;
        if (e < ne) {
            float dot = 0.f;
            #pragma unroll
            for (int c = 0; c < 8; c++) {
                bf16x8 vv = *(bf16x8*)&sA[e * SX_STR + c * 8];
                #pragma unroll
                for (int ii = 0; ii < 8; ii++)
                    dot += (float)vv[ii] * sA2[(c * 8 + ii) * NHEADS + h];
            }
            scrS[(size_t)(e0 + e) * NHEADS + h] = __expf((dot + prm[PRM_AB2 + h]) * 0.125f);
        }
    }

    // Phase 5: GEMM2 H@W2T + b2 + edges0 -> new_edges
    {
        f32x4 c2[3] = {z, z, z};
        const int n = w * 16 + l15;
        const bf16* pW2 = W2T + (size_t)n * H1D + quad * 8;
        bf16x8 b2f = *(const bf16x8*)pW2;
        #pragma unroll 1
        for (int kk = 0; kk < 8; kk++) {
            bf16x8 b2n;
            if (kk < 7) b2n = *(const bf16x8*)(pW2 + (kk + 1) * 32);
            const int kc = kk * 32 + quad * 8;
            #pragma unroll
            for (int s2 = 0; s2 < 3; s2++) {
                bf16x8 a = *(bf16x8*)&sH[(s2 * 16 + l15) * SH_STR + kc];
                c2[s2] = __builtin_amdgcn_mfma_f32_16x16x32_bf16(a, b2f, c2[s2], 0, 0, 0);
            }
            if (kk < 7) b2f = b2n;
        }
        const float bb2 = prm[PRM_B2 + n];
        #pragma unroll
        for (int s2 = 0; s2 < 3; s2++)
            #pragma unroll
            for (int r = 0; r < 4; r++) {
                const int row = s2 * 16 + quad * 4 + r;
                if (row < ne) {
                    size_t off = (size_t)(e0 + row) * EDIM + n;
                    float ev = isb ? (float)((const bf16*)edges0)[off] : ((const float*)edges0)[off];
                    float v = c2[s2][r] + bb2 + ev;
                    if (isb) ((bf16*)outNE)[off] = (bf16)v;
                    else     ((float*)outNE)[off] = v;
                }
            }
    }
}

// ---------------- K_pool: gather-based segment softmax-pool ----------------
__global__ __launch_bounds__(256) void k_pool(const u32* __restrict__ cnt,
                                              const u32* __restrict__ order,
                                              const float* __restrict__ scrS,
                                              const void* __restrict__ nodes,
                                              void* __restrict__ d_out) {
    const int t = threadIdx.x;
    const bool isb = probe_bf16(nodes, t);
    const int ws = blockIdx.x * 4 + (t >> 6);    // segment id, 0..4095
    const int lane = t & 63, h = lane >> 4;
    const void* newE = d_out;

    const u32 n1 = min(cnt[ws], (u32)CAP);
    const u32 base = (u32)ws * CAP;
    float acc = 0.f, dsum = 0.f;
    u32 i = 0;
    for (; i + 4 <= n1; i += 4) {
        u32 ea = order[base + i], eb = order[base + i + 1];
        u32 ec = order[base + i + 2], ed = order[base + i + 3];
        float sa = scrS[(size_t)ea * NHEADS + h];
        float sb = scrS[(size_t)eb * NHEADS + h];
        float sc = scrS[(size_t)ec * NHEADS + h];
        float sd = scrS[(size_t)ed * NHEADS + h];
        float va = ldf(newE, (size_t)ea * EDIM + lane, isb);
        float vb = ldf(newE, (size_t)eb * EDIM + lane, isb);
        float vc = ldf(newE, (size_t)ec * EDIM + lane, isb);
        float vd = ldf(newE, (size_t)ed * EDIM + lane, isb);
        acc += va * sa + vb * sb + vc * sc + vd * sd;
        dsum += sa + sb + sc + sd;
    }
    for (; i < n1; i++) {
        u32 e = order[base + i];
        float s = scrS[(size_t)e * NHEADS + h];
        acc += ldf(newE, (size_t)e * EDIM + lane, isb) * s;
        dsum += s;
    }
    float r = (dsum > 0.f) ? acc / dsum : 0.f;
    size_t po = (size_t)E_TOT * OUTD + (size_t)ws * OUTD + lane;
    if (isb) ((bf16*)d_out)[po] = (bf16)r;
    else     ((float*)d_out)[po] = r;
}

static char* align_up(char* p, size_t a) {
    return (char*)(((uintptr_t)p + (a - 1)) & ~(uintptr_t)(a - 1));
}

extern "C" void kernel_launch(void* const* d_in, const int* in_sizes, int n_in,
                              void* d_out, int out_size, void* d_ws, size_t ws_size,
                              hipStream_t stream) {
    const void* nodes  = d_in[0];
    const void* edges0 = d_in[1];
    const void* globs  = d_in[2];
    const void* ln_g   = d_in[3];
    const void* ln_b   = d_in[4];
    const void* W1     = d_in[5];
    const void* b1     = d_in[6];
    const void* W2     = d_in[7];
    const void* b2     = d_in[8];
    const void* A1     = d_in[9];
    const void* ab1    = d_in[10];
    const void* A2     = d_in[11];
    const void* ab2    = d_in[12];
    const int*  bidx   = (const int*)d_in[13];
    const int*  sidx   = (const int*)d_in[14];
    const int*  ridx   = (const int*)d_in[15];

    char* p = (char*)d_ws;
    float*  prm    = (float*)p;   p = align_up(p + PRM_TOT * 4, 256);
    bf16*   W1eT   = (bf16*)p;    p = align_up(p + H1D * EDIM * 2, 256);
    bf16*   A1eT   = (bf16*)p;    p = align_up(p + AHD * EDIM * 2, 256);
    bf16*   W2T    = (bf16*)p;    p = align_up(p + H1D * OUTD * 2, 256);
    float*  Gvec   = (float*)p;   p += H1D * 4;
    float*  Cvec   = (float*)p;   p += H1D * 4;
    float*  GAv    = (float*)p;   p += AHD * 4;
    float*  CAv    = (float*)p;   p += AHD * 4;
    float*  Gltab  = (float*)p;   p += 8 * H1D * 4;
    float*  GlAtab = (float*)p;   p = align_up(p + 8 * AHD * 4, 256);
    float2* SQ     = (float2*)p;  p += (size_t)NND * 8;               // 32 KB
    float*  Stab   = (float*)p;   p += (size_t)NND * H1D * 4;         // 4 MB
    float*  Rtab   = (float*)p;   p += (size_t)NND * H1D * 4;         // 4 MB
    float*  SAtab  = (float*)p;   p += (size_t)NND * AHD * 4;         // 1 MB
    float*  RAtab  = (float*)p;   p += (size_t)NND * AHD * 4;         // 1 MB
    u32*    cnt    = (u32*)p;     p += NSEG * 4;                      // 16 KB
    u32*    order  = (u32*)p;     p += (size_t)NSEG * CAP * 4;        // 3 MB
    float*  scrS   = (float*)p;   p += (size_t)E_TOT * NHEADS * 4;    // 4 MB

    hipMemsetAsync(cnt, 0, NSEG * 4, stream);
    k_prep<<<dim3(KP_NBLK), dim3(256), 0, stream>>>(
        nodes, globs, W1, W2, A1, ln_g, ln_b, b1, b2, A2, ab1, ab2,
        bidx, ridx, W1eT, A1eT, W2T, prm,
        Gvec, Cvec, GAv, CAv, Gltab, GlAtab, SQ,
        Stab, Rtab, SAtab, RAtab, cnt, order);
    k_edge<<<dim3((E_TOT + TE - 1) / TE), dim3(256), 0, stream>>>(
        nodes, edges0, prm, bidx, sidx, ridx,
        W1eT, A1eT, W2T, Gvec, Cvec, GAv, CAv, Gltab, GlAtab, SQ,
        Stab, Rtab, SAtab, RAtab, d_out, scrS);
    k_pool<<<dim3(NSEG / 4), dim3(256), 0, stream>>>(cnt, order, scrS, nodes, d_out);
}

// Round 8
// 418.576 us; speedup vs baseline: 1.3778x; 1.3778x over previous
//
#include <hip/hip_runtime.h>
#include <hip/hip_bf16.h>
#include <cstdint>

typedef __bf16 bf16;
typedef __bf16 bf16x8 __attribute__((ext_vector_type(8)));
typedef float f32x4 __attribute__((ext_vector_type(4)));
typedef unsigned int u32;

#define E_TOT   262144
#define NNODE   512
#define NDIM    128
#define EDIM    64
#define GDIM    32
#define FIN     320
#define XD      352   // FIN + CTX(32)
#define H1D     256
#define OUTD    64
#define AHD     64
#define NHEADS  4
#define NSEG    4096
#define TE      48    // edges per block (4 blocks/CU)
#define CAP     192   // bucket capacity; counts ~Poisson(64), P(>=192) < 1e-50

#define SX_STR  360   // 720B = 180 words, %32=20 -> 2-way alias (free)
#define SH_STR  264   // 528B = 132 words, %32=4  -> 2-way
#define SA_STR  72    // 144B = 36 words,  %32=4  -> 2-way

// fp32 params block layout (floats). k_edge uses B2/A2/AB2; b1/ab1/LN folded away.
#define PRM_LNG 0
#define PRM_LNB 320
#define PRM_B1  640
#define PRM_B2  896
#define PRM_A2  960
#define PRM_AB1 1216
#define PRM_AB2 1280
#define PRM_TOT 1284

// LDS layout (bytes). sX 48x360x2=34560; sH (48x264x2=25344) overlays sX head;
// sA (48x72x2=6912) overlays sX at 25600 (ends 32512, inside 34560).
// LN gamma/beta no longer staged (folded into weights + G/C vectors).
#define SMEM_SX    0
#define SMEM_A2    34560   // float[256]  = 1024
#define SMEM_IDX   35584   // 3 x int[48] = 576
#define SMEM_MU    36160   // float2[48]  = 384  ({rstd, -rstd*mu} per edge row)
#define SMEM_TOT   36544   // x4 = 146176 <= 160K -> 4 blocks/CU
#define SMEM_SA    25600

// k_prep block sections
#define KP_W1T   0      // 352 blocks: W1T [256][352], gamma-folded rows k<320
#define KP_W2T   352    // 64:  W2T [64][256]
#define KP_A1T   416    // 88:  A1T [64][352], gamma-folded rows k<320
#define KP_PRM   504    // 6:   params copy
#define KP_GC    510    // 40:  Gvec/Cvec/GAv/CAv partial sums (atomicAdd, pre-zeroed)
#define KP_SCAT  550    // 1024: bucket scatter
#define KP_NBLK  1574

__device__ __forceinline__ float siluf(float v) {
    return v / (1.0f + __expf(-v));
}

__device__ __forceinline__ float ldf(const void* p, size_t i, bool isb) {
    return isb ? (float)((const bf16*)p)[i] : ((const float*)p)[i];
}

// Per-wave dtype probe: 1=bf16 data, 0=fp32 data. Reads first 256 u16 of nodes.
__device__ __forceinline__ bool probe_bf16(const void* nodes, int t) {
    const unsigned short* u16 = (const unsigned short*)nodes;
    int lane = t & 63;
    int pl = 0;
    #pragma unroll
    for (int i = 0; i < 4; i++) {
        unsigned short u = u16[lane * 4 + i];
        int expo = (u >> 7) & 0xFF;
        pl += (((u & 0x7FFF) == 0) || (expo >= 97 && expo <= 137)) ? 1 : 0;
    }
    #pragma unroll
    for (int m = 1; m < 64; m <<= 1) pl += __shfl_xor(pl, m);
    return pl >= 240;
}

// ---------------- K_prep: gamma-folded transposes + G/C vectors + scatter ----------------
__global__ __launch_bounds__(256) void k_prep(
    const void* __restrict__ nodes,
    const void* __restrict__ W1, const void* __restrict__ W2, const void* __restrict__ A1,
    const void* __restrict__ ln_g, const void* __restrict__ ln_b,
    const void* __restrict__ b1, const void* __restrict__ b2,
    const void* __restrict__ A2, const void* __restrict__ ab1, const void* __restrict__ ab2,
    const int* __restrict__ bidx, const int* __restrict__ ridx,
    bf16* __restrict__ W1T, bf16* __restrict__ W2T, bf16* __restrict__ A1T,
    float* __restrict__ prm,
    float* __restrict__ Gvec, float* __restrict__ Cvec,
    float* __restrict__ GAv,  float* __restrict__ CAv,
    u32* __restrict__ cnt, u32* __restrict__ order) {
    int b = blockIdx.x, t = threadIdx.x;
    if (b >= KP_SCAT) {                             // bucket scatter (cnt pre-zeroed)
        int ge = (b - KP_SCAT) * 256 + t;
        int seg = bidx[ge] * NNODE + ridx[ge];
        u32 pos = atomicAdd(&cnt[seg], 1u);
        if (pos < CAP) order[(size_t)seg * CAP + pos] = (u32)ge;
        return;
    }
    bool isb = probe_bf16(nodes, t);
    if (b < KP_W2T) {                               // W1 row k=b -> W1T[n][k], gamma-folded
        int k = b, n = t;
        float g = (k < FIN) ? ldf(ln_g, k, isb) : 1.0f;
        W1T[n * XD + k] = (bf16)(ldf(W1, (size_t)k * H1D + n, isb) * g);
    } else if (b < KP_A1T) {                        // W2 [256][64] -> W2T [64][256]
        int i = (b - KP_W2T) * 256 + t;
        int k = i / OUTD, n = i % OUTD;
        W2T[n * H1D + k] = (bf16)ldf(W2, i, isb);
    } else if (b < KP_PRM) {                        // A1 [352][64] -> A1T [64][352], folded
        int i = (b - KP_A1T) * 256 + t;
        int k = i >> 6, n = i & 63;
        float g = (k < FIN) ? ldf(ln_g, k, isb) : 1.0f;
        A1T[n * XD + k] = (bf16)(ldf(A1, i, isb) * g);
    } else if (b < KP_GC) {                         // params -> fp32 block
        int i = (b - KP_PRM) * 256 + t;
        if (i < PRM_TOT) {
            const void* src; int off;
            if (i < 320)       { src = ln_g; off = i; }
            else if (i < 640)  { src = ln_b; off = i - 320; }
            else if (i < 896)  { src = b1;   off = i - 640; }
            else if (i < 960)  { src = b2;   off = i - 896; }
            else if (i < 1216) { src = A2;   off = i - 960; }
            else if (i < 1280) { src = ab1;  off = i - 1216; }
            else               { src = ab2;  off = i - 1280; }
            prm[i] = ldf(src, off, isb);
        }
    } else {                                        // G/C partial sums, 8 k's per block
        int j = b - KP_GC;                          // 0..39
        float g = 0.f, c = 0.f;
        #pragma unroll
        for (int kk = 0; kk < 8; kk++) {
            int k = j * 8 + kk;
            float gam = ldf(ln_g, k, isb), bet = ldf(ln_b, k, isb);
            float wv = ldf(W1, (size_t)k * H1D + t, isb);
            g += gam * wv; c += bet * wv;
        }
        if (j == 0) c += ldf(b1, t, isb);
        atomicAdd(&Gvec[t], g);
        atomicAdd(&Cvec[t], c);
        if (t < AHD) {
            float gA = 0.f, cA = 0.f;
            #pragma unroll
            for (int kk = 0; kk < 8; kk++) {
                int k = j * 8 + kk;
                float wv = ldf(A1, (size_t)k * AHD + t, isb);
                gA += ldf(ln_g, k, isb) * wv;
                cA += ldf(ln_b, k, isb) * wv;
            }
            if (j == 0) cA += ldf(ab1, t, isb);
            atomicAdd(&GAv[t], gA);
            atomicAdd(&CAv[t], cA);
        }
    }
}

// ---------------- K1: fused per-edge-tile kernel (R6 structure + LN-apply fold) ----------------
__global__ __launch_bounds__(256, 4) void k_edge(
    const void* __restrict__ nodes, const void* __restrict__ edges0,
    const void* __restrict__ globs, const float* __restrict__ prm,
    const int* __restrict__ bidx, const int* __restrict__ sidx,
    const int* __restrict__ ridx,
    const bf16* __restrict__ W1T, const bf16* __restrict__ W2T,
    const bf16* __restrict__ A1T,
    const float* __restrict__ Gvec, const float* __restrict__ Cvec,
    const float* __restrict__ GAv,  const float* __restrict__ CAv,
    void* __restrict__ outNE, float* __restrict__ scrS) {

    __shared__ __align__(16) char smem[SMEM_TOT];
    bf16*   sX   = (bf16*)(smem + SMEM_SX);
    bf16*   sH   = (bf16*)(smem + SMEM_SX);     // overlay after GEMM1 barrier
    bf16*   sA   = (bf16*)(smem + SMEM_SA);     // overlay of sX mid-region
    float*  sA2  = (float*)(smem + SMEM_A2);
    int*    sBi  = (int*)(smem + SMEM_IDX);
    int*    sSi  = sBi + TE;
    int*    sRi  = sBi + 2 * TE;
    float2* sMu  = (float2*)(smem + SMEM_MU);   // {rstd, -rstd*mu} per edge row

    const int t  = threadIdx.x;
    const int e0 = blockIdx.x * TE;
    const int ne = min(TE, E_TOT - e0);          // tail block: 16
    const bool isb = probe_bf16(nodes, t);

    // Phase 0: stage indices + A2 weights
    if (t < TE) {
        int ge = e0 + t;
        if (t < ne) {
            sBi[t] = bidx[ge]; sSi[t] = sidx[ge]; sRi[t] = ridx[ge];
        } else {
            sBi[t] = 0; sSi[t] = 0; sRi[t] = 0;
        }
    } else if (t >= 64 && t < 128) {
        ((float4*)sA2)[t - 64] = ((const float4*)(prm + PRM_A2))[t - 64];
    }
    __syncthreads();

    // Phase 1: gather RAW values -> sX (no LN apply; gamma lives in W1T/A1T,
    // mu/rstd applied in the epilogue). Stats computed over the 320 LN'd dims;
    // globs written pre-scaled by sd = 1/rstd so the epilogue's rstd* cancels.
    {
        const int eh = t >> 3, gl = t & 7;
        for (int half = 0; half < 2; half++) {
            const int e = half * 32 + eh;
            if (e >= TE) break;
            if (e >= ne) {               // tail: zero-fill so GEMMs stay finite
                bf16x8 zz = {};
                #pragma unroll
                for (int j = 0; j < 6; j++) {
                    int c = gl + j * 8;
                    if (c < 44) *(bf16x8*)&sX[e * SX_STR + c * 8] = zz;
                }
                if (gl == 0) sMu[e] = make_float2(1.f, 0.f);
                continue;
            }
            const int ge = e0 + e;
            const int bi = sBi[e], si = sSi[e], ri = sRi[e];
            float v[40];
            bf16x8 xr[5];
            #pragma unroll
            for (int j = 0; j < 5; j++) {
                const int c = gl + j * 8;
                const void* base; size_t off;
                if (c < 8)       { base = edges0; off = (size_t)ge * EDIM + c * 8; }
                else if (c < 24) { base = nodes;  off = (size_t)(bi * NNODE + si) * NDIM + (c - 8) * 8; }
                else             { base = nodes;  off = (size_t)(bi * NNODE + ri) * NDIM + (c - 24) * 8; }
                if (isb) {
                    xr[j] = *(const bf16x8*)((const bf16*)base + off);
                    #pragma unroll
                    for (int ii = 0; ii < 8; ii++) v[j * 8 + ii] = (float)xr[j][ii];
                } else {
                    const float* sf = (const float*)base + off;
                    float4 f0 = ((const float4*)sf)[0];
                    float4 f1 = ((const float4*)sf)[1];
                    v[j*8+0]=f0.x; v[j*8+1]=f0.y; v[j*8+2]=f0.z; v[j*8+3]=f0.w;
                    v[j*8+4]=f1.x; v[j*8+5]=f1.y; v[j*8+6]=f1.z; v[j*8+7]=f1.w;
                    #pragma unroll
                    for (int ii = 0; ii < 8; ii++) xr[j][ii] = (bf16)v[j * 8 + ii];
                }
            }
            float s = 0.f, sq = 0.f;
            #pragma unroll
            for (int ii = 0; ii < 40; ii++) { s += v[ii]; sq += v[ii] * v[ii]; }
            #pragma unroll
            for (int m = 1; m < 8; m <<= 1) { s += __shfl_xor(s, m); sq += __shfl_xor(sq, m); }
            float mean = s * (1.0f / FIN);
            float var  = sq * (1.0f / FIN) - mean * mean;
            float rstd = rsqrtf(var + 1e-5f);
            float sd   = (var + 1e-5f) * rstd;       // 1/rstd
            if (gl == 0) sMu[e] = make_float2(rstd, -rstd * mean);
            #pragma unroll
            for (int j = 0; j < 5; j++) {
                const int c = gl + j * 8;
                *(bf16x8*)&sX[e * SX_STR + c * 8] = xr[j];
            }
            if (gl < 4) {   // globs chunk c = 40+gl, pre-scaled by sd
                const int c = 40 + gl;
                size_t off = (size_t)bi * GDIM + gl * 8;
                bf16x8 o;
                if (isb) {
                    bf16x8 gr = *(const bf16x8*)((const bf16*)globs + off);
                    #pragma unroll
                    for (int ii = 0; ii < 8; ii++) o[ii] = (bf16)((float)gr[ii] * sd);
                } else {
                    const float* sf = (const float*)globs + off;
                    float4 f0 = ((const float4*)sf)[0];
                    float4 f1 = ((const float4*)sf)[1];
                    o[0]=(bf16)(f0.x*sd); o[1]=(bf16)(f0.y*sd); o[2]=(bf16)(f0.z*sd); o[3]=(bf16)(f0.w*sd);
                    o[4]=(bf16)(f1.x*sd); o[5]=(bf16)(f1.y*sd); o[6]=(bf16)(f1.z*sd); o[7]=(bf16)(f1.w*sd);
                }
                *(bf16x8*)&sX[e * SX_STR + c * 8] = o;
            }
        }
    }
    __syncthreads();

    const int w = t >> 6, lane = t & 63, quad = lane >> 4, l15 = lane & 15;
    f32x4 z = {0.f, 0.f, 0.f, 0.f};

    // Phase 2: GEMM1 X(48x352)@W1T(->256) + X@A1T(->64), B-frags double-buffered
    f32x4 acc[3][4], accA[3];
    #pragma unroll
    for (int s2 = 0; s2 < 3; s2++) { accA[s2] = z; for (int i = 0; i < 4; i++) acc[s2][i] = z; }
    {
        const bf16* pW = W1T + (size_t)(w * 64 + l15) * XD + quad * 8;
        const bf16* pA = A1T + (size_t)(w * 16 + l15) * XD + quad * 8;
        bf16x8 bw[4], ba;
        #pragma unroll
        for (int i = 0; i < 4; i++) bw[i] = *(const bf16x8*)(pW + (size_t)i * 16 * XD);
        ba = *(const bf16x8*)pA;
        #pragma unroll 1
        for (int kk = 0; kk < 11; kk++) {
            bf16x8 bwn[4], ban;
            if (kk < 10) {
                #pragma unroll
                for (int i = 0; i < 4; i++) bwn[i] = *(const bf16x8*)(pW + (size_t)i * 16 * XD + (kk + 1) * 32);
                ban = *(const bf16x8*)(pA + (kk + 1) * 32);
            }
            const int kc = kk * 32 + quad * 8;
            bf16x8 a[3];
            #pragma unroll
            for (int s2 = 0; s2 < 3; s2++) a[s2] = *(bf16x8*)&sX[(s2 * 16 + l15) * SX_STR + kc];
            #pragma unroll
            for (int i = 0; i < 4; i++)
                #pragma unroll
                for (int s2 = 0; s2 < 3; s2++)
                    acc[s2][i] = __builtin_amdgcn_mfma_f32_16x16x32_bf16(a[s2], bw[i], acc[s2][i], 0, 0, 0);
            #pragma unroll
            for (int s2 = 0; s2 < 3; s2++)
                accA[s2] = __builtin_amdgcn_mfma_f32_16x16x32_bf16(a[s2], ba, accA[s2], 0, 0, 0);
            if (kk < 10) {
                #pragma unroll
                for (int i = 0; i < 4; i++) bw[i] = bwn[i];
                ba = ban;
            }
        }
    }
    __syncthreads();   // all sX reads done before overlay writes

    // Phase 3: epilogue val = rstd*acc + (-rstd*mu)*G + C -> silu -> sH / sA
    #pragma unroll 1
    for (int i = 0; i < 4; i++) {
        const int n = w * 64 + i * 16 + l15;
        const float Gn = Gvec[n], Cn = Cvec[n];
        #pragma unroll
        for (int s2 = 0; s2 < 3; s2++)
            #pragma unroll
            for (int r = 0; r < 4; r++) {
                const int row = s2 * 16 + quad * 4 + r;
                float2 mr = sMu[row];
                float val = mr.x * acc[s2][i][r] + mr.y * Gn + Cn;
                sH[row * SH_STR + n] = (bf16)siluf(val);
            }
    }
    {
        const int n = w * 16 + l15;
        const float Gn = GAv[n], Cn = CAv[n];
        #pragma unroll
        for (int s2 = 0; s2 < 3; s2++)
            #pragma unroll
            for (int r = 0; r < 4; r++) {
                const int row = s2 * 16 + quad * 4 + r;
                float2 mr = sMu[row];
                float val = mr.x * accA[s2][r] + mr.y * Gn + Cn;
                sA[row * SA_STR + n] = (bf16)siluf(val);
            }
    }
    __syncthreads();

    // Phase 4: scores = exp((silu(.)@A2 + ab2)/8) -> plain global stream
    if (t < TE * NHEADS) {
        const int e = t >> 2, h = t & 3;
        if (e < ne) {
            float dot = 0.f;
            #pragma unroll
            for (int c = 0; c < 8; c++) {
                bf16x8 vv = *(bf16x8*)&sA[e * SA_STR + c * 8];
                #pragma unroll
                for (int ii = 0; ii < 8; ii++)
                    dot += (float)vv[ii] * sA2[(c * 8 + ii) * NHEADS + h];
            }
            scrS[(size_t)(e0 + e) * NHEADS + h] = __expf((dot + prm[PRM_AB2 + h]) * 0.125f);
        }
    }

    // Phase 5: GEMM2 H@W2T + b2 + edges0 -> new_edges
    {
        f32x4 c2[3] = {z, z, z};
        const int n = w * 16 + l15;
        const bf16* pW2 = W2T + (size_t)n * H1D + quad * 8;
        bf16x8 b2f = *(const bf16x8*)pW2;
        #pragma unroll 1
        for (int kk = 0; kk < 8; kk++) {
            bf16x8 b2n;
            if (kk < 7) b2n = *(const bf16x8*)(pW2 + (kk + 1) * 32);
            const int kc = kk * 32 + quad * 8;
            #pragma unroll
            for (int s2 = 0; s2 < 3; s2++) {
                bf16x8 a = *(bf16x8*)&sH[(s2 * 16 + l15) * SH_STR + kc];
                c2[s2] = __builtin_amdgcn_mfma_f32_16x16x32_bf16(a, b2f, c2[s2], 0, 0, 0);
            }
            if (kk < 7) b2f = b2n;
        }
        const float bb2 = prm[PRM_B2 + n];
        #pragma unroll
        for (int s2 = 0; s2 < 3; s2++)
            #pragma unroll
            for (int r = 0; r < 4; r++) {
                const int row = s2 * 16 + quad * 4 + r;
                if (row < ne) {
                    size_t off = (size_t)(e0 + row) * EDIM + n;
                    float ev = isb ? (float)((const bf16*)edges0)[off] : ((const float*)edges0)[off];
                    float v = c2[s2][r] + bb2 + ev;
                    if (isb) ((bf16*)outNE)[off] = (bf16)v;
                    else     ((float*)outNE)[off] = v;
                }
            }
    }
}

// ---------------- K_pool: gather-based segment softmax-pool ----------------
__global__ __launch_bounds__(256) void k_pool(const u32* __restrict__ cnt,
                                              const u32* __restrict__ order,
                                              const float* __restrict__ scrS,
                                              const void* __restrict__ nodes,
                                              void* __restrict__ d_out) {
    const int t = threadIdx.x;
    const bool isb = probe_bf16(nodes, t);
    const int ws = blockIdx.x * 4 + (t >> 6);    // segment id, 0..4095
    const int lane = t & 63, h = lane >> 4;
    const void* newE = d_out;

    const u32 n1 = min(cnt[ws], (u32)CAP);
    const u32 base = (u32)ws * CAP;
    float acc = 0.f, dsum = 0.f;
    u32 i = 0;
    for (; i + 4 <= n1; i += 4) {
        u32 ea = order[base + i], eb = order[base + i + 1];
        u32 ec = order[base + i + 2], ed = order[base + i + 3];
        float sa = scrS[(size_t)ea * NHEADS + h];
        float sb = scrS[(size_t)eb * NHEADS + h];
        float sc = scrS[(size_t)ec * NHEADS + h];
        float sd = scrS[(size_t)ed * NHEADS + h];
        float va = ldf(newE, (size_t)ea * EDIM + lane, isb);
        float vb = ldf(newE, (size_t)eb * EDIM + lane, isb);
        float vc = ldf(newE, (size_t)ec * EDIM + lane, isb);
        float vd = ldf(newE, (size_t)ed * EDIM + lane, isb);
        acc += va * sa + vb * sb + vc * sc + vd * sd;
        dsum += sa + sb + sc + sd;
    }
    for (; i < n1; i++) {
        u32 e = order[base + i];
        float s = scrS[(size_t)e * NHEADS + h];
        acc += ldf(newE, (size_t)e * EDIM + lane, isb) * s;
        dsum += s;
    }
    float r = (dsum > 0.f) ? acc / dsum : 0.f;
    size_t po = (size_t)E_TOT * OUTD + (size_t)ws * OUTD + lane;
    if (isb) ((bf16*)d_out)[po] = (bf16)r;
    else     ((float*)d_out)[po] = r;
}

static char* align_up(char* p, size_t a) {
    return (char*)(((uintptr_t)p + (a - 1)) & ~(uintptr_t)(a - 1));
}

extern "C" void kernel_launch(void* const* d_in, const int* in_sizes, int n_in,
                              void* d_out, int out_size, void* d_ws, size_t ws_size,
                              hipStream_t stream) {
    const void* nodes  = d_in[0];
    const void* edges0 = d_in[1];
    const void* globs  = d_in[2];
    const void* ln_g   = d_in[3];
    const void* ln_b   = d_in[4];
    const void* W1     = d_in[5];
    const void* b1     = d_in[6];
    const void* W2     = d_in[7];
    const void* b2     = d_in[8];
    const void* A1     = d_in[9];
    const void* ab1    = d_in[10];
    const void* A2     = d_in[11];
    const void* ab2    = d_in[12];
    const int*  bidx   = (const int*)d_in[13];
    const int*  sidx   = (const int*)d_in[14];
    const int*  ridx   = (const int*)d_in[15];

    char* p = (char*)d_ws;
    float* prm    = (float*)p;  p = align_up(p + PRM_TOT * 4, 256);
    bf16*  W1T    = (bf16*)p;   p = align_up(p + XD * H1D * 2, 256);
    bf16*  W2T    = (bf16*)p;   p = align_up(p + H1D * OUTD * 2, 256);
    bf16*  A1T    = (bf16*)p;   p = align_up(p + XD * AHD * 2, 256);
    u32*   cnt    = (u32*)p;    p += NSEG * 4;                      // 16 KB
    float* Gvec   = (float*)p;  p += H1D * 4;                       // zeroed with cnt
    float* Cvec   = (float*)p;  p += H1D * 4;
    float* GAv    = (float*)p;  p += AHD * 4;
    float* CAv    = (float*)p;  p = align_up(p + AHD * 4, 256);
    u32*   order  = (u32*)p;    p += (size_t)NSEG * CAP * 4;        // 3 MB
    float* scrS   = (float*)p;  p += (size_t)E_TOT * NHEADS * 4;    // 4 MB

    hipMemsetAsync(cnt, 0, NSEG * 4 + (H1D + H1D + AHD + AHD) * 4, stream);
    k_prep<<<dim3(KP_NBLK), dim3(256), 0, stream>>>(
        nodes, W1, W2, A1, ln_g, ln_b, b1, b2, A2, ab1, ab2,
        bidx, ridx, W1T, W2T, A1T, prm, Gvec, Cvec, GAv, CAv, cnt, order);
    k_edge<<<dim3((E_TOT + TE - 1) / TE), dim3(256), 0, stream>>>(
        nodes, edges0, globs, prm, bidx, sidx, ridx,
        W1T, W2T, A1T, Gvec, Cvec, GAv, CAv, d_out, scrS);
    k_pool<<<dim3(NSEG / 4), dim3(256), 0, stream>>>(cnt, order, scrS, nodes, d_out);
}

// Round 9
// 417.582 us; speedup vs baseline: 1.3811x; 1.0024x over previous
//
#include <hip/hip_runtime.h>
#include <hip/hip_bf16.h>
#include <cstdint>

typedef __bf16 bf16;
typedef __bf16 bf16x8 __attribute__((ext_vector_type(8)));
typedef float f32x4 __attribute__((ext_vector_type(4)));
typedef unsigned int u32;

#define E_TOT   262144
#define NNODE   512
#define NDIM    128
#define EDIM    64
#define GDIM    32
#define FIN     320
#define XD      352   // FIN + CTX(32)
#define H1D     256
#define OUTD    64
#define AHD     64
#define NHEADS  4
#define NSEG    4096
#define TE      48    // edges per block (4 blocks/CU)
#define CAP     192   // bucket capacity; counts ~Poisson(64), P(>=192) < 1e-50

#define SX_STR  360   // 720B = 180 words, %32=20 -> 2-way alias (free)
#define SH_STR  264   // 528B = 132 words, %32=4  -> 2-way
#define SA_STR  72    // 144B = 36 words,  %32=4  -> 2-way

// fp32 params block layout (floats). k_edge uses B2/A2/AB2; b1/ab1/LN folded away.
#define PRM_LNG 0
#define PRM_LNB 320
#define PRM_B1  640
#define PRM_B2  896
#define PRM_A2  960
#define PRM_AB1 1216
#define PRM_AB2 1280
#define PRM_TOT 1284

// LDS layout (bytes). sX 48x360x2=34560; sH (48x264x2=25344) overlays sX head;
// sA (48x72x2=6912) overlays sX at 25600 (ends 32512, inside 34560).
#define SMEM_SX    0
#define SMEM_A2    34560   // float[256]  = 1024
#define SMEM_IDX   35584   // 3 x int[48] = 576
#define SMEM_MU    36160   // float2[48]  = 384  ({rstd, -rstd*mu} per edge row)
#define SMEM_TOT   36544   // x4 = 146176 <= 160K -> 4 blocks/CU
#define SMEM_SA    25600

// k_prep block sections
#define KP_W1T   0      // 352 blocks: W1T [256][352], gamma-folded rows k<320
#define KP_W2T   352    // 64:  W2T [64][256]
#define KP_A1T   416    // 88:  A1T [64][352], gamma-folded rows k<320
#define KP_PRM   504    // 6:   params copy
#define KP_GC    510    // 40:  Gvec/Cvec/GAv/CAv partial sums (atomicAdd, pre-zeroed)
#define KP_SCAT  550    // 1024: bucket scatter
#define KP_NBLK  1574

__device__ __forceinline__ float siluf(float v) {
    return v / (1.0f + __expf(-v));
}

__device__ __forceinline__ float ldf(const void* p, size_t i, bool isb) {
    return isb ? (float)((const bf16*)p)[i] : ((const float*)p)[i];
}

// Per-wave dtype probe: 1=bf16 data, 0=fp32 data. Reads first 256 u16 of nodes.
__device__ __forceinline__ bool probe_bf16(const void* nodes, int t) {
    const unsigned short* u16 = (const unsigned short*)nodes;
    int lane = t & 63;
    int pl = 0;
    #pragma unroll
    for (int i = 0; i < 4; i++) {
        unsigned short u = u16[lane * 4 + i];
        int expo = (u >> 7) & 0xFF;
        pl += (((u & 0x7FFF) == 0) || (expo >= 97 && expo <= 137)) ? 1 : 0;
    }
    #pragma unroll
    for (int m = 1; m < 64; m <<= 1) pl += __shfl_xor(pl, m);
    return pl >= 240;
}

// ---------------- K_prep: gamma-folded transposes + G/C vectors + scatter ----------------
__global__ __launch_bounds__(256) void k_prep(
    const void* __restrict__ nodes,
    const void* __restrict__ W1, const void* __restrict__ W2, const void* __restrict__ A1,
    const void* __restrict__ ln_g, const void* __restrict__ ln_b,
    const void* __restrict__ b1, const void* __restrict__ b2,
    const void* __restrict__ A2, const void* __restrict__ ab1, const void* __restrict__ ab2,
    const int* __restrict__ bidx, const int* __restrict__ ridx,
    bf16* __restrict__ W1T, bf16* __restrict__ W2T, bf16* __restrict__ A1T,
    float* __restrict__ prm,
    float* __restrict__ Gvec, float* __restrict__ Cvec,
    float* __restrict__ GAv,  float* __restrict__ CAv,
    u32* __restrict__ cnt, u32* __restrict__ order) {
    int b = blockIdx.x, t = threadIdx.x;
    if (b >= KP_SCAT) {                             // bucket scatter (cnt pre-zeroed)
        int ge = (b - KP_SCAT) * 256 + t;
        int seg = bidx[ge] * NNODE + ridx[ge];
        u32 pos = atomicAdd(&cnt[seg], 1u);
        if (pos < CAP) order[(size_t)seg * CAP + pos] = (u32)ge;
        return;
    }
    bool isb = probe_bf16(nodes, t);
    if (b < KP_W2T) {                               // W1 row k=b -> W1T[n][k], gamma-folded
        int k = b, n = t;
        float g = (k < FIN) ? ldf(ln_g, k, isb) : 1.0f;
        W1T[n * XD + k] = (bf16)(ldf(W1, (size_t)k * H1D + n, isb) * g);
    } else if (b < KP_A1T) {                        // W2 [256][64] -> W2T [64][256]
        int i = (b - KP_W2T) * 256 + t;
        int k = i / OUTD, n = i % OUTD;
        W2T[n * H1D + k] = (bf16)ldf(W2, i, isb);
    } else if (b < KP_PRM) {                        // A1 [352][64] -> A1T [64][352], folded
        int i = (b - KP_A1T) * 256 + t;
        int k = i >> 6, n = i & 63;
        float g = (k < FIN) ? ldf(ln_g, k, isb) : 1.0f;
        A1T[n * XD + k] = (bf16)(ldf(A1, i, isb) * g);
    } else if (b < KP_GC) {                         // params -> fp32 block
        int i = (b - KP_PRM) * 256 + t;
        if (i < PRM_TOT) {
            const void* src; int off;
            if (i < 320)       { src = ln_g; off = i; }
            else if (i < 640)  { src = ln_b; off = i - 320; }
            else if (i < 896)  { src = b1;   off = i - 640; }
            else if (i < 960)  { src = b2;   off = i - 896; }
            else if (i < 1216) { src = A2;   off = i - 960; }
            else if (i < 1280) { src = ab1;  off = i - 1216; }
            else               { src = ab2;  off = i - 1280; }
            prm[i] = ldf(src, off, isb);
        }
    } else {                                        // G/C partial sums, 8 k's per block
        int j = b - KP_GC;                          // 0..39
        float g = 0.f, c = 0.f;
        #pragma unroll
        for (int kk = 0; kk < 8; kk++) {
            int k = j * 8 + kk;
            float gam = ldf(ln_g, k, isb), bet = ldf(ln_b, k, isb);
            float wv = ldf(W1, (size_t)k * H1D + t, isb);
            g += gam * wv; c += bet * wv;
        }
        if (j == 0) c += ldf(b1, t, isb);
        atomicAdd(&Gvec[t], g);
        atomicAdd(&Cvec[t], c);
        if (t < AHD) {
            float gA = 0.f, cA = 0.f;
            #pragma unroll
            for (int kk = 0; kk < 8; kk++) {
                int k = j * 8 + kk;
                float wv = ldf(A1, (size_t)k * AHD + t, isb);
                gA += ldf(ln_g, k, isb) * wv;
                cA += ldf(ln_b, k, isb) * wv;
            }
            if (j == 0) cA += ldf(ab1, t, isb);
            atomicAdd(&GAv[t], gA);
            atomicAdd(&CAv[t], cA);
        }
    }
}

// ---------------- K1: fused per-edge-tile kernel (streaming phase 1, no spills) ----------------
__global__ __launch_bounds__(256, 4) void k_edge(
    const void* __restrict__ nodes, const void* __restrict__ edges0,
    const void* __restrict__ globs, const float* __restrict__ prm,
    const int* __restrict__ bidx, const int* __restrict__ sidx,
    const int* __restrict__ ridx,
    const bf16* __restrict__ W1T, const bf16* __restrict__ W2T,
    const bf16* __restrict__ A1T,
    const float* __restrict__ Gvec, const float* __restrict__ Cvec,
    const float* __restrict__ GAv,  const float* __restrict__ CAv,
    void* __restrict__ outNE, float* __restrict__ scrS) {

    __shared__ __align__(16) char smem[SMEM_TOT];
    bf16*   sX   = (bf16*)(smem + SMEM_SX);
    bf16*   sH   = (bf16*)(smem + SMEM_SX);     // overlay after GEMM1 barrier
    bf16*   sA   = (bf16*)(smem + SMEM_SA);     // overlay of sX mid-region
    float*  sA2  = (float*)(smem + SMEM_A2);
    int*    sBi  = (int*)(smem + SMEM_IDX);
    int*    sSi  = sBi + TE;
    int*    sRi  = sBi + 2 * TE;
    float2* sMu  = (float2*)(smem + SMEM_MU);   // {rstd, -rstd*mu} per edge row

    const int t  = threadIdx.x;
    const int e0 = blockIdx.x * TE;
    const int ne = min(TE, E_TOT - e0);          // tail block: 16
    const bool isb = probe_bf16(nodes, t);

    // Phase 0: stage indices + A2 weights
    if (t < TE) {
        int ge = e0 + t;
        if (t < ne) {
            sBi[t] = bidx[ge]; sSi[t] = sidx[ge]; sRi[t] = ridx[ge];
        } else {
            sBi[t] = 0; sSi[t] = 0; sRi[t] = 0;
        }
    } else if (t >= 64 && t < 128) {
        ((float4*)sA2)[t - 64] = ((const float4*)(prm + PRM_A2))[t - 64];
    }
    __syncthreads();

    // Phase 1 (STREAMING): raw values -> sX immediately; stats accumulated on
    // the fly. Live set per iteration: one bf16x8 + (s,sq) -- no v[40]/xr[5]
    // arrays, no spill (R8's 2.75x traffic was scratch spill from keeping both).
    // gamma lives in W1T/A1T; mu/rstd applied in the epilogue; globs chunk
    // pre-scaled by sd = 1/rstd so the epilogue's rstd* cancels.
    {
        const int eh = t >> 3, gl = t & 7;
        for (int half = 0; half < 2; half++) {
            const int e = half * 32 + eh;
            if (e >= TE) break;
            if (e >= ne) {               // tail: zero-fill so GEMMs stay finite
                bf16x8 zz = {};
                #pragma unroll
                for (int j = 0; j < 6; j++) {
                    int c = gl + j * 8;
                    if (c < 44) *(bf16x8*)&sX[e * SX_STR + c * 8] = zz;
                }
                if (gl == 0) sMu[e] = make_float2(1.f, 0.f);
                continue;
            }
            const int ge = e0 + e;
            const int bi = sBi[e], si = sSi[e], ri = sRi[e];
            float s = 0.f, sq = 0.f;
            #pragma unroll
            for (int j = 0; j < 5; j++) {
                const int c = gl + j * 8;
                const void* base; size_t off;
                if (c < 8)       { base = edges0; off = (size_t)ge * EDIM + c * 8; }
                else if (c < 24) { base = nodes;  off = (size_t)(bi * NNODE + si) * NDIM + (c - 8) * 8; }
                else             { base = nodes;  off = (size_t)(bi * NNODE + ri) * NDIM + (c - 24) * 8; }
                bf16x8 o;
                if (isb) {
                    o = *(const bf16x8*)((const bf16*)base + off);
                    #pragma unroll
                    for (int ii = 0; ii < 8; ii++) { float f = (float)o[ii]; s += f; sq += f * f; }
                } else {
                    const float* sf = (const float*)base + off;
                    float4 f0 = ((const float4*)sf)[0];
                    float4 f1 = ((const float4*)sf)[1];
                    float vv[8] = {f0.x, f0.y, f0.z, f0.w, f1.x, f1.y, f1.z, f1.w};
                    #pragma unroll
                    for (int ii = 0; ii < 8; ii++) { s += vv[ii]; sq += vv[ii] * vv[ii]; o[ii] = (bf16)vv[ii]; }
                }
                *(bf16x8*)&sX[e * SX_STR + c * 8] = o;   // raw store, no LN apply
            }
            #pragma unroll
            for (int m = 1; m < 8; m <<= 1) { s += __shfl_xor(s, m); sq += __shfl_xor(sq, m); }
            float mean = s * (1.0f / FIN);
            float var  = sq * (1.0f / FIN) - mean * mean;
            float rstd = rsqrtf(var + 1e-5f);
            float sd   = (var + 1e-5f) * rstd;       // 1/rstd
            if (gl == 0) sMu[e] = make_float2(rstd, -rstd * mean);
            if (gl < 4) {   // globs chunk c = 40+gl, pre-scaled by sd
                const int c = 40 + gl;
                size_t off = (size_t)bi * GDIM + gl * 8;
                bf16x8 o;
                if (isb) {
                    bf16x8 gr = *(const bf16x8*)((const bf16*)globs + off);
                    #pragma unroll
                    for (int ii = 0; ii < 8; ii++) o[ii] = (bf16)((float)gr[ii] * sd);
                } else {
                    const float* sf = (const float*)globs + off;
                    float4 f0 = ((const float4*)sf)[0];
                    float4 f1 = ((const float4*)sf)[1];
                    o[0]=(bf16)(f0.x*sd); o[1]=(bf16)(f0.y*sd); o[2]=(bf16)(f0.z*sd); o[3]=(bf16)(f0.w*sd);
                    o[4]=(bf16)(f1.x*sd); o[5]=(bf16)(f1.y*sd); o[6]=(bf16)(f1.z*sd); o[7]=(bf16)(f1.w*sd);
                }
                *(bf16x8*)&sX[e * SX_STR + c * 8] = o;
            }
        }
    }
    __syncthreads();

    const int w = t >> 6, lane = t & 63, quad = lane >> 4, l15 = lane & 15;
    f32x4 z = {0.f, 0.f, 0.f, 0.f};

    // Phase 2: GEMM1 X(48x352)@W1T(->256) + X@A1T(->64), B-frags double-buffered
    f32x4 acc[3][4], accA[3];
    #pragma unroll
    for (int s2 = 0; s2 < 3; s2++) { accA[s2] = z; for (int i = 0; i < 4; i++) acc[s2][i] = z; }
    {
        const bf16* pW = W1T + (size_t)(w * 64 + l15) * XD + quad * 8;
        const bf16* pA = A1T + (size_t)(w * 16 + l15) * XD + quad * 8;
        bf16x8 bw[4], ba;
        #pragma unroll
        for (int i = 0; i < 4; i++) bw[i] = *(const bf16x8*)(pW + (size_t)i * 16 * XD);
        ba = *(const bf16x8*)pA;
        #pragma unroll 1
        for (int kk = 0; kk < 11; kk++) {
            bf16x8 bwn[4], ban;
            if (kk < 10) {
                #pragma unroll
                for (int i = 0; i < 4; i++) bwn[i] = *(const bf16x8*)(pW + (size_t)i * 16 * XD + (kk + 1) * 32);
                ban = *(const bf16x8*)(pA + (kk + 1) * 32);
            }
            const int kc = kk * 32 + quad * 8;
            bf16x8 a[3];
            #pragma unroll
            for (int s2 = 0; s2 < 3; s2++) a[s2] = *(bf16x8*)&sX[(s2 * 16 + l15) * SX_STR + kc];
            #pragma unroll
            for (int i = 0; i < 4; i++)
                #pragma unroll
                for (int s2 = 0; s2 < 3; s2++)
                    acc[s2][i] = __builtin_amdgcn_mfma_f32_16x16x32_bf16(a[s2], bw[i], acc[s2][i], 0, 0, 0);
            #pragma unroll
            for (int s2 = 0; s2 < 3; s2++)
                accA[s2] = __builtin_amdgcn_mfma_f32_16x16x32_bf16(a[s2], ba, accA[s2], 0, 0, 0);
            if (kk < 10) {
                #pragma unroll
                for (int i = 0; i < 4; i++) bw[i] = bwn[i];
                ba = ban;
            }
        }
    }
    __syncthreads();   // all sX reads done before overlay writes

    // Phase 3: epilogue val = rstd*acc + (-rstd*mu)*G + C -> silu -> sH / sA
    #pragma unroll 1
    for (int i = 0; i < 4; i++) {
        const int n = w * 64 + i * 16 + l15;
        const float Gn = Gvec[n], Cn = Cvec[n];
        #pragma unroll
        for (int s2 = 0; s2 < 3; s2++)
            #pragma unroll
            for (int r = 0; r < 4; r++) {
                const int row = s2 * 16 + quad * 4 + r;
                float2 mr = sMu[row];
                float val = mr.x * acc[s2][i][r] + mr.y * Gn + Cn;
                sH[row * SH_STR + n] = (bf16)siluf(val);
            }
    }
    {
        const int n = w * 16 + l15;
        const float Gn = GAv[n], Cn = CAv[n];
        #pragma unroll
        for (int s2 = 0; s2 < 3; s2++)
            #pragma unroll
            for (int r = 0; r < 4; r++) {
                const int row = s2 * 16 + quad * 4 + r;
                float2 mr = sMu[row];
                float val = mr.x * accA[s2][r] + mr.y * Gn + Cn;
                sA[row * SA_STR + n] = (bf16)siluf(val);
            }
    }
    __syncthreads();

    // Phase 4: scores = exp((silu(.)@A2 + ab2)/8) -> plain global stream
    if (t < TE * NHEADS) {
        const int e = t >> 2, h = t & 3;
        if (e < ne) {
            float dot = 0.f;
            #pragma unroll
            for (int c = 0; c < 8; c++) {
                bf16x8 vv = *(bf16x8*)&sA[e * SA_STR + c * 8];
                #pragma unroll
                for (int ii = 0; ii < 8; ii++)
                    dot += (float)vv[ii] * sA2[(c * 8 + ii) * NHEADS + h];
            }
            scrS[(size_t)(e0 + e) * NHEADS + h] = __expf((dot + prm[PRM_AB2 + h]) * 0.125f);
        }
    }

    // Phase 5: GEMM2 H@W2T + b2 + edges0 -> new_edges
    {
        f32x4 c2[3] = {z, z, z};
        const int n = w * 16 + l15;
        const bf16* pW2 = W2T + (size_t)n * H1D + quad * 8;
        bf16x8 b2f = *(const bf16x8*)pW2;
        #pragma unroll 1
        for (int kk = 0; kk < 8; kk++) {
            bf16x8 b2n;
            if (kk < 7) b2n = *(const bf16x8*)(pW2 + (kk + 1) * 32);
            const int kc = kk * 32 + quad * 8;
            #pragma unroll
            for (int s2 = 0; s2 < 3; s2++) {
                bf16x8 a = *(bf16x8*)&sH[(s2 * 16 + l15) * SH_STR + kc];
                c2[s2] = __builtin_amdgcn_mfma_f32_16x16x32_bf16(a, b2f, c2[s2], 0, 0, 0);
            }
            if (kk < 7) b2f = b2n;
        }
        const float bb2 = prm[PRM_B2 + n];
        #pragma unroll
        for (int s2 = 0; s2 < 3; s2++)
            #pragma unroll
            for (int r = 0; r < 4; r++) {
                const int row = s2 * 16 + quad * 4 + r;
                if (row < ne) {
                    size_t off = (size_t)(e0 + row) * EDIM + n;
                    float ev = isb ? (float)((const bf16*)edges0)[off] : ((const float*)edges0)[off];
                    float v = c2[s2][r] + bb2 + ev;
                    if (isb) ((bf16*)outNE)[off] = (bf16)v;
                    else     ((float*)outNE)[off] = v;
                }
            }
    }
}

// ---------------- K_pool: gather-based segment softmax-pool ----------------
__global__ __launch_bounds__(256) void k_pool(const u32* __restrict__ cnt,
                                              const u32* __restrict__ order,
                                              const float* __restrict__ scrS,
                                              const void* __restrict__ nodes,
                                              void* __restrict__ d_out) {
    const int t = threadIdx.x;
    const bool isb = probe_bf16(nodes, t);
    const int ws = blockIdx.x * 4 + (t >> 6);    // segment id, 0..4095
    const int lane = t & 63, h = lane >> 4;
    const void* newE = d_out;

    const u32 n1 = min(cnt[ws], (u32)CAP);
    const u32 base = (u32)ws * CAP;
    float acc = 0.f, dsum = 0.f;
    u32 i = 0;
    for (; i + 4 <= n1; i += 4) {
        u32 ea = order[base + i], eb = order[base + i + 1];
        u32 ec = order[base + i + 2], ed = order[base + i + 3];
        float sa = scrS[(size_t)ea * NHEADS + h];
        float sb = scrS[(size_t)eb * NHEADS + h];
        float sc = scrS[(size_t)ec * NHEADS + h];
        float sd = scrS[(size_t)ed * NHEADS + h];
        float va = ldf(newE, (size_t)ea * EDIM + lane, isb);
        float vb = ldf(newE, (size_t)eb * EDIM + lane, isb);
        float vc = ldf(newE, (size_t)ec * EDIM + lane, isb);
        float vd = ldf(newE, (size_t)ed * EDIM + lane, isb);
        acc += va * sa + vb * sb + vc * sc + vd * sd;
        dsum += sa + sb + sc + sd;
    }
    for (; i < n1; i++) {
        u32 e = order[base + i];
        float s = scrS[(size_t)e * NHEADS + h];
        acc += ldf(newE, (size_t)e * EDIM + lane, isb) * s;
        dsum += s;
    }
    float r = (dsum > 0.f) ? acc / dsum : 0.f;
    size_t po = (size_t)E_TOT * OUTD + (size_t)ws * OUTD + lane;
    if (isb) ((bf16*)d_out)[po] = (bf16)r;
    else     ((float*)d_out)[po] = r;
}

static char* align_up(char* p, size_t a) {
    return (char*)(((uintptr_t)p + (a - 1)) & ~(uintptr_t)(a - 1));
}

extern "C" void kernel_launch(void* const* d_in, const int* in_sizes, int n_in,
                              void* d_out, int out_size, void* d_ws, size_t ws_size,
                              hipStream_t stream) {
    const void* nodes  = d_in[0];
    const void* edges0 = d_in[1];
    const void* globs  = d_in[2];
    const void* ln_g   = d_in[3];
    const void* ln_b   = d_in[4];
    const void* W1     = d_in[5];
    const void* b1     = d_in[6];
    const void* W2     = d_in[7];
    const void* b2     = d_in[8];
    const void* A1     = d_in[9];
    const void* ab1    = d_in[10];
    const void* A2     = d_in[11];
    const void* ab2    = d_in[12];
    const int*  bidx   = (const int*)d_in[13];
    const int*  sidx   = (const int*)d_in[14];
    const int*  ridx   = (const int*)d_in[15];

    char* p = (char*)d_ws;
    float* prm    = (float*)p;  p = align_up(p + PRM_TOT * 4, 256);
    bf16*  W1T    = (bf16*)p;   p = align_up(p + XD * H1D * 2, 256);
    bf16*  W2T    = (bf16*)p;   p = align_up(p + H1D * OUTD * 2, 256);
    bf16*  A1T    = (bf16*)p;   p = align_up(p + XD * AHD * 2, 256);
    u32*   cnt    = (u32*)p;    p += NSEG * 4;                      // 16 KB
    float* Gvec   = (float*)p;  p += H1D * 4;                       // zeroed with cnt
    float* Cvec   = (float*)p;  p += H1D * 4;
    float* GAv    = (float*)p;  p += AHD * 4;
    float* CAv    = (float*)p;  p = align_up(p + AHD * 4, 256);
    u32*   order  = (u32*)p;    p += (size_t)NSEG * CAP * 4;        // 3 MB
    float* scrS   = (float*)p;  p += (size_t)E_TOT * NHEADS * 4;    // 4 MB

    hipMemsetAsync(cnt, 0, NSEG * 4 + (H1D + H1D + AHD + AHD) * 4, stream);
    k_prep<<<dim3(KP_NBLK), dim3(256), 0, stream>>>(
        nodes, W1, W2, A1, ln_g, ln_b, b1, b2, A2, ab1, ab2,
        bidx, ridx, W1T, W2T, A1T, prm, Gvec, Cvec, GAv, CAv, cnt, order);
    k_edge<<<dim3((E_TOT + TE - 1) / TE), dim3(256), 0, stream>>>(
        nodes, edges0, globs, prm, bidx, sidx, ridx,
        W1T, W2T, A1T, Gvec, Cvec, GAv, CAv, d_out, scrS);
    k_pool<<<dim3(NSEG / 4), dim3(256), 0, stream>>>(cnt, order, scrS, nodes, d_out);
}

// Round 10
// 336.028 us; speedup vs baseline: 1.7163x; 1.2427x over previous
//
#include <hip/hip_runtime.h>
#include <hip/hip_bf16.h>
#include <cstdint>

typedef __bf16 bf16;
typedef __bf16 bf16x8 __attribute__((ext_vector_type(8)));
typedef float f32x4 __attribute__((ext_vector_type(4)));
typedef unsigned int u32;

#define E_TOT   262144
#define NNODE   512
#define NDIM    128
#define EDIM    64
#define GDIM    32
#define FIN     320
#define XD      352   // FIN + CTX(32)
#define H1D     256
#define OUTD    64
#define AHD     64
#define NHEADS  4
#define NSEG    4096
#define TE      48    // edges per block (4 blocks/CU)
#define CAP     192   // bucket capacity; counts ~Poisson(64), P(>=192) < 1e-50

#define SX_STR  360   // 720B = 180 words, %32=20 -> 2-way alias (free)
#define SH_STR  264   // 528B = 132 words, %32=4  -> 2-way
#define SA_STR  72    // 144B = 36 words,  %32=4  -> 2-way

// fp32 params block layout (floats). k_edge uses B2/A2/AB2; b1/ab1/LN folded away.
#define PRM_LNG 0
#define PRM_LNB 320
#define PRM_B1  640
#define PRM_B2  896
#define PRM_A2  960
#define PRM_AB1 1216
#define PRM_AB2 1280
#define PRM_TOT 1284

// LDS layout (bytes). sX 48x360x2=34560; sH (48x264x2=25344) overlays sX head;
// sA (48x72x2=6912) overlays sX at 25600 (ends 32512, inside 34560).
#define SMEM_SX    0
#define SMEM_A2    34560   // float[256]  = 1024
#define SMEM_IDX   35584   // 3 x int[48] = 576
#define SMEM_MU    36160   // float2[48]  = 384  ({rstd, -rstd*mu} per edge row)
#define SMEM_TOT   36544   // x4 = 146176 <= 160K -> 4 blocks/CU
#define SMEM_SA    25600

// k_prep block sections
#define KP_W1T   0      // 352 blocks: W1T [256][352], gamma-folded rows k<320
#define KP_W2T   352    // 64:  W2T [64][256]
#define KP_A1T   416    // 88:  A1T [64][352], gamma-folded rows k<320
#define KP_PRM   504    // 6:   params copy
#define KP_GC    510    // 40:  Gvec/Cvec/GAv/CAv partial sums (atomicAdd, pre-zeroed)
#define KP_SCAT  550    // 1024: bucket scatter
#define KP_NBLK  1574

__device__ __forceinline__ float siluf(float v) {
    return v / (1.0f + __expf(-v));
}

__device__ __forceinline__ float ldf(const void* p, size_t i, bool isb) {
    return isb ? (float)((const bf16*)p)[i] : ((const float*)p)[i];
}

// Per-wave dtype probe: 1=bf16 data, 0=fp32 data. Reads first 256 u16 of nodes.
__device__ __forceinline__ bool probe_bf16(const void* nodes, int t) {
    const unsigned short* u16 = (const unsigned short*)nodes;
    int lane = t & 63;
    int pl = 0;
    #pragma unroll
    for (int i = 0; i < 4; i++) {
        unsigned short u = u16[lane * 4 + i];
        int expo = (u >> 7) & 0xFF;
        pl += (((u & 0x7FFF) == 0) || (expo >= 97 && expo <= 137)) ? 1 : 0;
    }
    #pragma unroll
    for (int m = 1; m < 64; m <<= 1) pl += __shfl_xor(pl, m);
    return pl >= 240;
}

// ---------------- K_prep: gamma-folded transposes + G/C vectors + scatter ----------------
__global__ __launch_bounds__(256) void k_prep(
    const void* __restrict__ nodes,
    const void* __restrict__ W1, const void* __restrict__ W2, const void* __restrict__ A1,
    const void* __restrict__ ln_g, const void* __restrict__ ln_b,
    const void* __restrict__ b1, const void* __restrict__ b2,
    const void* __restrict__ A2, const void* __restrict__ ab1, const void* __restrict__ ab2,
    const int* __restrict__ bidx, const int* __restrict__ ridx,
    bf16* __restrict__ W1T, bf16* __restrict__ W2T, bf16* __restrict__ A1T,
    float* __restrict__ prm,
    float* __restrict__ Gvec, float* __restrict__ Cvec,
    float* __restrict__ GAv,  float* __restrict__ CAv,
    u32* __restrict__ cnt, u32* __restrict__ order) {
    int b = blockIdx.x, t = threadIdx.x;
    if (b >= KP_SCAT) {                             // bucket scatter (cnt pre-zeroed)
        int ge = (b - KP_SCAT) * 256 + t;
        int seg = bidx[ge] * NNODE + ridx[ge];
        u32 pos = atomicAdd(&cnt[seg], 1u);
        if (pos < CAP) order[(size_t)seg * CAP + pos] = (u32)ge;
        return;
    }
    bool isb = probe_bf16(nodes, t);
    if (b < KP_W2T) {                               // W1 row k=b -> W1T[n][k], gamma-folded
        int k = b, n = t;
        float g = (k < FIN) ? ldf(ln_g, k, isb) : 1.0f;
        W1T[n * XD + k] = (bf16)(ldf(W1, (size_t)k * H1D + n, isb) * g);
    } else if (b < KP_A1T) {                        // W2 [256][64] -> W2T [64][256]
        int i = (b - KP_W2T) * 256 + t;
        int k = i / OUTD, n = i % OUTD;
        W2T[n * H1D + k] = (bf16)ldf(W2, i, isb);
    } else if (b < KP_PRM) {                        // A1 [352][64] -> A1T [64][352], folded
        int i = (b - KP_A1T) * 256 + t;
        int k = i >> 6, n = i & 63;
        float g = (k < FIN) ? ldf(ln_g, k, isb) : 1.0f;
        A1T[n * XD + k] = (bf16)(ldf(A1, i, isb) * g);
    } else if (b < KP_GC) {                         // params -> fp32 block
        int i = (b - KP_PRM) * 256 + t;
        if (i < PRM_TOT) {
            const void* src; int off;
            if (i < 320)       { src = ln_g; off = i; }
            else if (i < 640)  { src = ln_b; off = i - 320; }
            else if (i < 896)  { src = b1;   off = i - 640; }
            else if (i < 960)  { src = b2;   off = i - 896; }
            else if (i < 1216) { src = A2;   off = i - 960; }
            else if (i < 1280) { src = ab1;  off = i - 1216; }
            else               { src = ab2;  off = i - 1280; }
            prm[i] = ldf(src, off, isb);
        }
    } else {                                        // G/C partial sums, 8 k's per block
        int j = b - KP_GC;                          // 0..39
        float g = 0.f, c = 0.f;
        #pragma unroll
        for (int kk = 0; kk < 8; kk++) {
            int k = j * 8 + kk;
            float gam = ldf(ln_g, k, isb), bet = ldf(ln_b, k, isb);
            float wv = ldf(W1, (size_t)k * H1D + t, isb);
            g += gam * wv; c += bet * wv;
        }
        if (j == 0) c += ldf(b1, t, isb);
        atomicAdd(&Gvec[t], g);
        atomicAdd(&Cvec[t], c);
        if (t < AHD) {
            float gA = 0.f, cA = 0.f;
            #pragma unroll
            for (int kk = 0; kk < 8; kk++) {
                int k = j * 8 + kk;
                float wv = ldf(A1, (size_t)k * AHD + t, isb);
                gA += ldf(ln_g, k, isb) * wv;
                cA += ldf(ln_b, k, isb) * wv;
            }
            if (j == 0) cA += ldf(ab1, t, isb);
            atomicAdd(&GAv[t], gA);
            atomicAdd(&CAv[t], cA);
        }
    }
}

// ---------------- K1: fused per-edge-tile kernel (streaming phase 1 + LN fold) ----------------
__global__ __launch_bounds__(256, 4) void k_edge(
    const void* __restrict__ nodes, const void* __restrict__ edges0,
    const void* __restrict__ globs, const float* __restrict__ prm,
    const int* __restrict__ bidx, const int* __restrict__ sidx,
    const int* __restrict__ ridx,
    const bf16* __restrict__ W1T, const bf16* __restrict__ W2T,
    const bf16* __restrict__ A1T,
    const float* __restrict__ Gvec, const float* __restrict__ Cvec,
    const float* __restrict__ GAv,  const float* __restrict__ CAv,
    void* __restrict__ outNE, float* __restrict__ scrS) {

    __shared__ __align__(16) char smem[SMEM_TOT];
    bf16*   sX   = (bf16*)(smem + SMEM_SX);
    bf16*   sH   = (bf16*)(smem + SMEM_SX);     // overlay after GEMM1 barrier
    bf16*   sA   = (bf16*)(smem + SMEM_SA);     // overlay of sX mid-region
    float*  sA2  = (float*)(smem + SMEM_A2);
    int*    sBi  = (int*)(smem + SMEM_IDX);
    int*    sSi  = sBi + TE;
    int*    sRi  = sBi + 2 * TE;
    float2* sMu  = (float2*)(smem + SMEM_MU);   // {rstd, -rstd*mu} per edge row

    const int t  = threadIdx.x;
    const int e0 = blockIdx.x * TE;
    const int ne = min(TE, E_TOT - e0);          // tail block: 16
    const bool isb = probe_bf16(nodes, t);

    // Phase 0: stage indices + A2 weights
    if (t < TE) {
        int ge = e0 + t;
        if (t < ne) {
            sBi[t] = bidx[ge]; sSi[t] = sidx[ge]; sRi[t] = ridx[ge];
        } else {
            sBi[t] = 0; sSi[t] = 0; sRi[t] = 0;
        }
    } else if (t >= 64 && t < 128) {
        ((float4*)sA2)[t - 64] = ((const float4*)(prm + PRM_A2))[t - 64];
    }
    __syncthreads();

    // Phase 1 (STREAMING): raw values -> sX immediately; stats on the fly.
    // gamma lives in W1T/A1T; mu/rstd applied in the epilogue; globs chunk
    // pre-scaled by sd = 1/rstd so the epilogue's rstd* cancels.
    {
        const int eh = t >> 3, gl = t & 7;
        for (int half = 0; half < 2; half++) {
            const int e = half * 32 + eh;
            if (e >= TE) break;
            if (e >= ne) {               // tail: zero-fill so GEMMs stay finite
                bf16x8 zz = {};
                #pragma unroll
                for (int j = 0; j < 6; j++) {
                    int c = gl + j * 8;
                    if (c < 44) *(bf16x8*)&sX[e * SX_STR + c * 8] = zz;
                }
                if (gl == 0) sMu[e] = make_float2(1.f, 0.f);
                continue;
            }
            const int ge = e0 + e;
            const int bi = sBi[e], si = sSi[e], ri = sRi[e];
            float s = 0.f, sq = 0.f;
            #pragma unroll
            for (int j = 0; j < 5; j++) {
                const int c = gl + j * 8;
                const void* base; size_t off;
                if (c < 8)       { base = edges0; off = (size_t)ge * EDIM + c * 8; }
                else if (c < 24) { base = nodes;  off = (size_t)(bi * NNODE + si) * NDIM + (c - 8) * 8; }
                else             { base = nodes;  off = (size_t)(bi * NNODE + ri) * NDIM + (c - 24) * 8; }
                bf16x8 o;
                if (isb) {
                    o = *(const bf16x8*)((const bf16*)base + off);
                    #pragma unroll
                    for (int ii = 0; ii < 8; ii++) { float f = (float)o[ii]; s += f; sq += f * f; }
                } else {
                    const float* sf = (const float*)base + off;
                    float4 f0 = ((const float4*)sf)[0];
                    float4 f1 = ((const float4*)sf)[1];
                    float vv[8] = {f0.x, f0.y, f0.z, f0.w, f1.x, f1.y, f1.z, f1.w};
                    #pragma unroll
                    for (int ii = 0; ii < 8; ii++) { s += vv[ii]; sq += vv[ii] * vv[ii]; o[ii] = (bf16)vv[ii]; }
                }
                *(bf16x8*)&sX[e * SX_STR + c * 8] = o;   // raw store, no LN apply
            }
            #pragma unroll
            for (int m = 1; m < 8; m <<= 1) { s += __shfl_xor(s, m); sq += __shfl_xor(sq, m); }
            float mean = s * (1.0f / FIN);
            float var  = sq * (1.0f / FIN) - mean * mean;
            float rstd = rsqrtf(var + 1e-5f);
            float sd   = (var + 1e-5f) * rstd;       // 1/rstd
            if (gl == 0) sMu[e] = make_float2(rstd, -rstd * mean);
            if (gl < 4) {   // globs chunk c = 40+gl, pre-scaled by sd
                const int c = 40 + gl;
                size_t off = (size_t)bi * GDIM + gl * 8;
                bf16x8 o;
                if (isb) {
                    bf16x8 gr = *(const bf16x8*)((const bf16*)globs + off);
                    #pragma unroll
                    for (int ii = 0; ii < 8; ii++) o[ii] = (bf16)((float)gr[ii] * sd);
                } else {
                    const float* sf = (const float*)globs + off;
                    float4 f0 = ((const float4*)sf)[0];
                    float4 f1 = ((const float4*)sf)[1];
                    o[0]=(bf16)(f0.x*sd); o[1]=(bf16)(f0.y*sd); o[2]=(bf16)(f0.z*sd); o[3]=(bf16)(f0.w*sd);
                    o[4]=(bf16)(f1.x*sd); o[5]=(bf16)(f1.y*sd); o[6]=(bf16)(f1.z*sd); o[7]=(bf16)(f1.w*sd);
                }
                *(bf16x8*)&sX[e * SX_STR + c * 8] = o;
            }
        }
    }
    __syncthreads();

    const int w = t >> 6, lane = t & 63, quad = lane >> 4, l15 = lane & 15;
    f32x4 z = {0.f, 0.f, 0.f, 0.f};

    // Phase 2: GEMM1 X(48x352)@W1T(->256) + X@A1T(->64), B-frags double-buffered
    f32x4 acc[3][4], accA[3];
    #pragma unroll
    for (int s2 = 0; s2 < 3; s2++) { accA[s2] = z; for (int i = 0; i < 4; i++) acc[s2][i] = z; }
    {
        const bf16* pW = W1T + (size_t)(w * 64 + l15) * XD + quad * 8;
        const bf16* pA = A1T + (size_t)(w * 16 + l15) * XD + quad * 8;
        bf16x8 bw[4], ba;
        #pragma unroll
        for (int i = 0; i < 4; i++) bw[i] = *(const bf16x8*)(pW + (size_t)i * 16 * XD);
        ba = *(const bf16x8*)pA;
        #pragma unroll 1
        for (int kk = 0; kk < 11; kk++) {
            bf16x8 bwn[4], ban;
            if (kk < 10) {
                #pragma unroll
                for (int i = 0; i < 4; i++) bwn[i] = *(const bf16x8*)(pW + (size_t)i * 16 * XD + (kk + 1) * 32);
                ban = *(const bf16x8*)(pA + (kk + 1) * 32);
            }
            const int kc = kk * 32 + quad * 8;
            bf16x8 a[3];
            #pragma unroll
            for (int s2 = 0; s2 < 3; s2++) a[s2] = *(bf16x8*)&sX[(s2 * 16 + l15) * SX_STR + kc];
            #pragma unroll
            for (int i = 0; i < 4; i++)
                #pragma unroll
                for (int s2 = 0; s2 < 3; s2++)
                    acc[s2][i] = __builtin_amdgcn_mfma_f32_16x16x32_bf16(a[s2], bw[i], acc[s2][i], 0, 0, 0);
            #pragma unroll
            for (int s2 = 0; s2 < 3; s2++)
                accA[s2] = __builtin_amdgcn_mfma_f32_16x16x32_bf16(a[s2], ba, accA[s2], 0, 0, 0);
            if (kk < 10) {
                #pragma unroll
                for (int i = 0; i < 4; i++) bw[i] = bwn[i];
                ba = ban;
            }
        }
    }
    __syncthreads();   // all sX reads done before overlay writes

    // Phase 3: epilogue val = rstd*acc + (-rstd*mu)*G + C -> silu -> sH / sA.
    // FULL unroll is load-bearing (rule #20): R7-R9 had `#pragma unroll 1` here,
    // which made `i` runtime -> acc[s2][i][r] runtime-indexed -> all 48 acc
    // floats spilled to scratch (~530 MB/dispatch round-trip, the R8/R9 traffic).
    #pragma unroll
    for (int i = 0; i < 4; i++) {
        const int n = w * 64 + i * 16 + l15;
        const float Gn = Gvec[n], Cn = Cvec[n];
        #pragma unroll
        for (int s2 = 0; s2 < 3; s2++)
            #pragma unroll
            for (int r = 0; r < 4; r++) {
                const int row = s2 * 16 + quad * 4 + r;
                float2 mr = sMu[row];
                float val = mr.x * acc[s2][i][r] + mr.y * Gn + Cn;
                sH[row * SH_STR + n] = (bf16)siluf(val);
            }
    }
    {
        const int n = w * 16 + l15;
        const float Gn = GAv[n], Cn = CAv[n];
        #pragma unroll
        for (int s2 = 0; s2 < 3; s2++)
            #pragma unroll
            for (int r = 0; r < 4; r++) {
                const int row = s2 * 16 + quad * 4 + r;
                float2 mr = sMu[row];
                float val = mr.x * accA[s2][r] + mr.y * Gn + Cn;
                sA[row * SA_STR + n] = (bf16)siluf(val);
            }
    }
    __syncthreads();

    // Phase 4: scores = exp((silu(.)@A2 + ab2)/8) -> plain global stream
    if (t < TE * NHEADS) {
        const int e = t >> 2, h = t & 3;
        if (e < ne) {
            float dot = 0.f;
            #pragma unroll
            for (int c = 0; c < 8; c++) {
                bf16x8 vv = *(bf16x8*)&sA[e * SA_STR + c * 8];
                #pragma unroll
                for (int ii = 0; ii < 8; ii++)
                    dot += (float)vv[ii] * sA2[(c * 8 + ii) * NHEADS + h];
            }
            scrS[(size_t)(e0 + e) * NHEADS + h] = __expf((dot + prm[PRM_AB2 + h]) * 0.125f);
        }
    }

    // Phase 5: GEMM2 H@W2T + b2 + edges0 -> new_edges
    {
        f32x4 c2[3] = {z, z, z};
        const int n = w * 16 + l15;
        const bf16* pW2 = W2T + (size_t)n * H1D + quad * 8;
        bf16x8 b2f = *(const bf16x8*)pW2;
        #pragma unroll 1
        for (int kk = 0; kk < 8; kk++) {
            bf16x8 b2n;
            if (kk < 7) b2n = *(const bf16x8*)(pW2 + (kk + 1) * 32);
            const int kc = kk * 32 + quad * 8;
            #pragma unroll
            for (int s2 = 0; s2 < 3; s2++) {
                bf16x8 a = *(bf16x8*)&sH[(s2 * 16 + l15) * SH_STR + kc];
                c2[s2] = __builtin_amdgcn_mfma_f32_16x16x32_bf16(a, b2f, c2[s2], 0, 0, 0);
            }
            if (kk < 7) b2f = b2n;
        }
        const float bb2 = prm[PRM_B2 + n];
        #pragma unroll
        for (int s2 = 0; s2 < 3; s2++)
            #pragma unroll
            for (int r = 0; r < 4; r++) {
                const int row = s2 * 16 + quad * 4 + r;
                if (row < ne) {
                    size_t off = (size_t)(e0 + row) * EDIM + n;
                    float ev = isb ? (float)((const bf16*)edges0)[off] : ((const float*)edges0)[off];
                    float v = c2[s2][r] + bb2 + ev;
                    if (isb) ((bf16*)outNE)[off] = (bf16)v;
                    else     ((float*)outNE)[off] = v;
                }
            }
    }
}

// ---------------- K_pool: gather-based segment softmax-pool ----------------
__global__ __launch_bounds__(256) void k_pool(const u32* __restrict__ cnt,
                                              const u32* __restrict__ order,
                                              const float* __restrict__ scrS,
                                              const void* __restrict__ nodes,
                                              void* __restrict__ d_out) {
    const int t = threadIdx.x;
    const bool isb = probe_bf16(nodes, t);
    const int ws = blockIdx.x * 4 + (t >> 6);    // segment id, 0..4095
    const int lane = t & 63, h = lane >> 4;
    const void* newE = d_out;

    const u32 n1 = min(cnt[ws], (u32)CAP);
    const u32 base = (u32)ws * CAP;
    float acc = 0.f, dsum = 0.f;
    u32 i = 0;
    for (; i + 4 <= n1; i += 4) {
        u32 ea = order[base + i], eb = order[base + i + 1];
        u32 ec = order[base + i + 2], ed = order[base + i + 3];
        float sa = scrS[(size_t)ea * NHEADS + h];
        float sb = scrS[(size_t)eb * NHEADS + h];
        float sc = scrS[(size_t)ec * NHEADS + h];
        float sd = scrS[(size_t)ed * NHEADS + h];
        float va = ldf(newE, (size_t)ea * EDIM + lane, isb);
        float vb = ldf(newE, (size_t)eb * EDIM + lane, isb);
        float vc = ldf(newE, (size_t)ec * EDIM + lane, isb);
        float vd = ldf(newE, (size_t)ed * EDIM + lane, isb);
        acc += va * sa + vb * sb + vc * sc + vd * sd;
        dsum += sa + sb + sc + sd;
    }
    for (; i < n1; i++) {
        u32 e = order[base + i];
        float s = scrS[(size_t)e * NHEADS + h];
        acc += ldf(newE, (size_t)e * EDIM + lane, isb) * s;
        dsum += s;
    }
    float r = (dsum > 0.f) ? acc / dsum : 0.f;
    size_t po = (size_t)E_TOT * OUTD + (size_t)ws * OUTD + lane;
    if (isb) ((bf16*)d_out)[po] = (bf16)r;
    else     ((float*)d_out)[po] = r;
}

static char* align_up(char* p, size_t a) {
    return (char*)(((uintptr_t)p + (a - 1)) & ~(uintptr_t)(a - 1));
}

extern "C" void kernel_launch(void* const* d_in, const int* in_sizes, int n_in,
                              void* d_out, int out_size, void* d_ws, size_t ws_size,
                              hipStream_t stream) {
    const void* nodes  = d_in[0];
    const void* edges0 = d_in[1];
    const void* globs  = d_in[2];
    const void* ln_g   = d_in[3];
    const void* ln_b   = d_in[4];
    const void* W1     = d_in[5];
    const void* b1     = d_in[6];
    const void* W2     = d_in[7];
    const void* b2     = d_in[8];
    const void* A1     = d_in[9];
    const void* ab1    = d_in[10];
    const void* A2     = d_in[11];
    const void* ab2    = d_in[12];
    const int*  bidx   = (const int*)d_in[13];
    const int*  sidx   = (const int*)d_in[14];
    const int*  ridx   = (const int*)d_in[15];

    char* p = (char*)d_ws;
    float* prm    = (float*)p;  p = align_up(p + PRM_TOT * 4, 256);
    bf16*  W1T    = (bf16*)p;   p = align_up(p + XD * H1D * 2, 256);
    bf16*  W2T    = (bf16*)p;   p = align_up(p + H1D * OUTD * 2, 256);
    bf16*  A1T    = (bf16*)p;   p = align_up(p + XD * AHD * 2, 256);
    u32*   cnt    = (u32*)p;    p += NSEG * 4;                      // 16 KB
    float* Gvec   = (float*)p;  p += H1D * 4;                       // zeroed with cnt
    float* Cvec   = (float*)p;  p += H1D * 4;
    float* GAv    = (float*)p;  p += AHD * 4;
    float* CAv    = (float*)p;  p = align_up(p + AHD * 4, 256);
    u32*   order  = (u32*)p;    p += (size_t)NSEG * CAP * 4;        // 3 MB
    float* scrS   = (float*)p;  p += (size_t)E_TOT * NHEADS * 4;    // 4 MB

    hipMemsetAsync(cnt, 0, NSEG * 4 + (H1D + H1D + AHD + AHD) * 4, stream);
    k_prep<<<dim3(KP_NBLK), dim3(256), 0, stream>>>(
        nodes, W1, W2, A1, ln_g, ln_b, b1, b2, A2, ab1, ab2,
        bidx, ridx, W1T, W2T, A1T, prm, Gvec, Cvec, GAv, CAv, cnt, order);
    k_edge<<<dim3((E_TOT + TE - 1) / TE), dim3(256), 0, stream>>>(
        nodes, edges0, globs, prm, bidx, sidx, ridx,
        W1T, W2T, A1T, Gvec, Cvec, GAv, CAv, d_out, scrS);
    k_pool<<<dim3(NSEG / 4), dim3(256), 0, stream>>>(cnt, order, scrS, nodes, d_out);
}

// Round 11
// 318.278 us; speedup vs baseline: 1.8120x; 1.0558x over previous
//
#include <hip/hip_runtime.h>
#include <hip/hip_bf16.h>
#include <cstdint>

typedef __bf16 bf16;
typedef __bf16 bf16x8 __attribute__((ext_vector_type(8)));
typedef float f32x4 __attribute__((ext_vector_type(4)));
typedef unsigned int u32;

#define E_TOT   262144
#define NNODE   512
#define NDIM    128
#define EDIM    64
#define GDIM    32
#define FIN     320
#define XD      352   // FIN + CTX(32)
#define H1D     256
#define OUTD    64
#define AHD     64
#define NHEADS  4
#define NSEG    4096
#define TE      48    // edges per block (4 blocks/CU)
#define CAP     192   // bucket capacity; counts ~Poisson(64), P(>=192) < 1e-50

#define SX_STR  360   // 720B = 180 words, %32=20 -> 2-way alias (free)
#define SH_STR  264   // 528B = 132 words, %32=4  -> 2-way
#define SA_STR  72    // 144B = 36 words,  %32=4  -> 2-way

// fp32 params block layout (floats)
#define PRM_LNG 0
#define PRM_LNB 320
#define PRM_B1  640
#define PRM_B2  896
#define PRM_A2  960
#define PRM_AB1 1216
#define PRM_AB2 1280
#define PRM_TOT 1284

// LDS layout (bytes). sX 48x360x2=34560; sH (48x264x2=25344) overlays sX head;
// sA (48x72x2=6912) overlays sX at 25600 (ends 32512, inside 34560).
// sIdx region is NEVER overlaid -> still valid for the end-of-kernel scatter.
#define SMEM_SX    0
#define SMEM_SA    25600
#define SMEM_A2    34560   // float[256]  = 1024
#define SMEM_LNG   35584   // float[320]  = 1280
#define SMEM_LNB   36864   // float[320]  = 1280
#define SMEM_IDX   38144   // 3 x int[48] = 576
#define SMEM_TOT   38720   // x4 = 154880 <= 160K -> 4 blocks/CU

#define KP_NBLK  511       // 352 W1T + 64 W2T + 88 A1T + 6 prm + 1 cnt-zero

__device__ __forceinline__ float siluf(float v) {
    return v / (1.0f + __expf(-v));
}

__device__ __forceinline__ float ldf(const void* p, size_t i, bool isb) {
    return isb ? (float)((const bf16*)p)[i] : ((const float*)p)[i];
}

// Per-wave dtype probe: 1=bf16 data, 0=fp32 data. Reads first 256 u16 of nodes.
__device__ __forceinline__ bool probe_bf16(const void* nodes, int t) {
    const unsigned short* u16 = (const unsigned short*)nodes;
    int lane = t & 63;
    int pl = 0;
    #pragma unroll
    for (int i = 0; i < 4; i++) {
        unsigned short u = u16[lane * 4 + i];
        int expo = (u >> 7) & 0xFF;
        pl += (((u & 0x7FFF) == 0) || (expo >= 97 && expo <= 137)) ? 1 : 0;
    }
    #pragma unroll
    for (int m = 1; m < 64; m <<= 1) pl += __shfl_xor(pl, m);
    return pl >= 240;
}

// ---------------- K_prep: weights transpose + params + cnt zero (no scatter pass) --------
__global__ __launch_bounds__(256) void k_prep(
    const void* __restrict__ nodes,
    const void* __restrict__ W1, const void* __restrict__ W2, const void* __restrict__ A1,
    const void* __restrict__ ln_g, const void* __restrict__ ln_b,
    const void* __restrict__ b1, const void* __restrict__ b2,
    const void* __restrict__ A2, const void* __restrict__ ab1, const void* __restrict__ ab2,
    bf16* __restrict__ W1T, bf16* __restrict__ W2T, bf16* __restrict__ A1T,
    float* __restrict__ prm, u32* __restrict__ cnt) {
    int b = blockIdx.x, t = threadIdx.x;
    if (b == 510) {                                 // zero cnt (4096 u32 = 1024 uint4)
        uint4 z4 = {0u, 0u, 0u, 0u};
        #pragma unroll
        for (int q = 0; q < 4; q++) ((uint4*)cnt)[t * 4 + q] = z4;
        return;
    }
    bool isb = probe_bf16(nodes, t);
    if (b < 352) {                                  // W1 [352][256] -> W1T [256][352]
        int i = b * 256 + t;
        int k = i / H1D, n = i % H1D;
        W1T[n * XD + k] = (bf16)ldf(W1, i, isb);
    } else if (b < 416) {                           // W2 [256][64] -> W2T [64][256]
        int i = (b - 352) * 256 + t;
        int k = i / OUTD, n = i % OUTD;
        W2T[n * H1D + k] = (bf16)ldf(W2, i, isb);
    } else if (b < 504) {                           // A1 [352][64] -> A1T [64][352]
        int i = (b - 416) * 256 + t;
        int k = i / AHD, n = i % AHD;
        A1T[n * XD + k] = (bf16)ldf(A1, i, isb);
    } else {                                        // params -> fp32 block (blocks 504..509)
        int i = (b - 504) * 256 + t;
        if (i < PRM_TOT) {
            const void* src; int off;
            if (i < 320)       { src = ln_g; off = i; }
            else if (i < 640)  { src = ln_b; off = i - 320; }
            else if (i < 896)  { src = b1;   off = i - 640; }
            else if (i < 960)  { src = b2;   off = i - 896; }
            else if (i < 1216) { src = A2;   off = i - 960; }
            else if (i < 1280) { src = ab1;  off = i - 1216; }
            else               { src = ab2;  off = i - 1280; }
            prm[i] = ldf(src, off, isb);
        }
    }
}

// ---------------- K1: fused per-edge-tile kernel (R6 body + tail scatter) ----------------
__global__ __launch_bounds__(256, 4) void k_edge(
    const void* __restrict__ nodes, const void* __restrict__ edges0,
    const void* __restrict__ globs, const float* __restrict__ prm,
    const int* __restrict__ bidx, const int* __restrict__ sidx,
    const int* __restrict__ ridx,
    const bf16* __restrict__ W1T, const bf16* __restrict__ W2T,
    const bf16* __restrict__ A1T,
    void* __restrict__ outNE, float* __restrict__ scrS,
    u32* __restrict__ cnt, u32* __restrict__ order) {

    __shared__ __align__(16) char smem[SMEM_TOT];
    bf16*  sX    = (bf16*)(smem + SMEM_SX);
    bf16*  sH    = (bf16*)(smem + SMEM_SX);     // overlay after GEMM1 barrier
    bf16*  sA    = (bf16*)(smem + SMEM_SA);     // overlay of sX mid-region
    float* sA2   = (float*)(smem + SMEM_A2);
    float* sLnG  = (float*)(smem + SMEM_LNG);
    float* sLnB  = (float*)(smem + SMEM_LNB);
    int*   sBi   = (int*)(smem + SMEM_IDX);
    int*   sSi   = sBi + TE;
    int*   sRi   = sBi + 2 * TE;

    const int t  = threadIdx.x;
    const int e0 = blockIdx.x * TE;
    const int ne = min(TE, E_TOT - e0);          // tail block: 16
    const bool isb = probe_bf16(nodes, t);

    // Phase 0: stage indices + LN params + A2 weights (R0/R6-proven staging)
    if (t < TE) {
        int ge = e0 + t;
        if (t < ne) {
            sBi[t] = bidx[ge]; sSi[t] = sidx[ge]; sRi[t] = ridx[ge];
        } else {
            sBi[t] = 0; sSi[t] = 0; sRi[t] = 0;
        }
    } else if (t < 128) {
        int c = t - 48;
        if (c < 80) ((float4*)sLnG)[c] = ((const float4*)(prm + PRM_LNG))[c];
    } else if (t < 208) {
        int c = t - 128;
        ((float4*)sLnB)[c] = ((const float4*)(prm + PRM_LNB))[c];
    } else {
        int c = t - 208;
        if (c < 32) {
            ((float4*)sA2)[c]      = ((const float4*)(prm + PRM_A2))[c];
            ((float4*)sA2)[c + 32] = ((const float4*)(prm + PRM_A2))[c + 32];
        }
    }
    __syncthreads();

    // Phase 1: merged gather + LayerNorm in registers (8 threads per edge)
    {
        const int eh = t >> 3, gl = t & 7;
        for (int half = 0; half < 2; half++) {
            const int e = half * 32 + eh;
            if (e >= TE) break;
            if (e >= ne) {               // tail: zero-fill so GEMMs stay finite
                bf16x8 zz = {};
                #pragma unroll
                for (int j = 0; j < 6; j++) {
                    int c = gl + j * 8;
                    if (c < 44) *(bf16x8*)&sX[e * SX_STR + c * 8] = zz;
                }
                continue;
            }
            const int ge = e0 + e;
            const int bi = sBi[e], si = sSi[e], ri = sRi[e];
            float v[40];
            #pragma unroll
            for (int j = 0; j < 5; j++) {
                const int c = gl + j * 8;
                const void* base; size_t off;
                if (c < 8)       { base = edges0; off = (size_t)ge * EDIM + c * 8; }
                else if (c < 24) { base = nodes;  off = (size_t)(bi * NNODE + si) * NDIM + (c - 8) * 8; }
                else             { base = nodes;  off = (size_t)(bi * NNODE + ri) * NDIM + (c - 24) * 8; }
                if (isb) {
                    bf16x8 x = *(const bf16x8*)((const bf16*)base + off);
                    #pragma unroll
                    for (int ii = 0; ii < 8; ii++) v[j * 8 + ii] = (float)x[ii];
                } else {
                    const float* sf = (const float*)base + off;
                    float4 f0 = ((const float4*)sf)[0];
                    float4 f1 = ((const float4*)sf)[1];
                    v[j*8+0]=f0.x; v[j*8+1]=f0.y; v[j*8+2]=f0.z; v[j*8+3]=f0.w;
                    v[j*8+4]=f1.x; v[j*8+5]=f1.y; v[j*8+6]=f1.z; v[j*8+7]=f1.w;
                }
            }
            float s = 0.f, sq = 0.f;
            #pragma unroll
            for (int ii = 0; ii < 40; ii++) { s += v[ii]; sq += v[ii] * v[ii]; }
            #pragma unroll
            for (int m = 1; m < 8; m <<= 1) { s += __shfl_xor(s, m); sq += __shfl_xor(sq, m); }
            float mean = s * (1.0f / FIN);
            float var  = sq * (1.0f / FIN) - mean * mean;
            float rstd = rsqrtf(var + 1e-5f);
            #pragma unroll
            for (int j = 0; j < 5; j++) {
                const int c = gl + j * 8;
                const float* gP = &sLnG[c * 8];
                const float* bP = &sLnB[c * 8];
                bf16x8 o;
                #pragma unroll
                for (int ii = 0; ii < 8; ii++)
                    o[ii] = (bf16)((v[j * 8 + ii] - mean) * rstd * gP[ii] + bP[ii]);
                *(bf16x8*)&sX[e * SX_STR + c * 8] = o;
            }
            if (gl < 4) {   // globs chunk c = 40+gl (not LayerNormed)
                const int c = 40 + gl;
                size_t off = (size_t)bi * GDIM + gl * 8;
                bf16x8 o;
                if (isb) {
                    o = *(const bf16x8*)((const bf16*)globs + off);
                } else {
                    const float* sf = (const float*)globs + off;
                    float4 f0 = ((const float4*)sf)[0];
                    float4 f1 = ((const float4*)sf)[1];
                    o[0]=(bf16)f0.x; o[1]=(bf16)f0.y; o[2]=(bf16)f0.z; o[3]=(bf16)f0.w;
                    o[4]=(bf16)f1.x; o[5]=(bf16)f1.y; o[6]=(bf16)f1.z; o[7]=(bf16)f1.w;
                }
                *(bf16x8*)&sX[e * SX_STR + c * 8] = o;
            }
        }
    }
    __syncthreads();

    const int w = t >> 6, lane = t & 63, quad = lane >> 4, l15 = lane & 15;
    f32x4 z = {0.f, 0.f, 0.f, 0.f};

    // Phase 2: GEMM1 X(48x352)@W1T(->256) + X@A1T(->64), B-frags double-buffered.
    // k-loop rolled (#pragma unroll 1): I$-thrash fix, -21 us + -60 MB traffic (R6).
    f32x4 acc[3][4], accA[3];
    #pragma unroll
    for (int s2 = 0; s2 < 3; s2++) { accA[s2] = z; for (int i = 0; i < 4; i++) acc[s2][i] = z; }
    {
        const bf16* pW = W1T + (size_t)(w * 64 + l15) * XD + quad * 8;
        const bf16* pA = A1T + (size_t)(w * 16 + l15) * XD + quad * 8;
        bf16x8 bw[4], ba;
        #pragma unroll
        for (int i = 0; i < 4; i++) bw[i] = *(const bf16x8*)(pW + (size_t)i * 16 * XD);
        ba = *(const bf16x8*)pA;
        #pragma unroll 1
        for (int kk = 0; kk < 11; kk++) {
            bf16x8 bwn[4], ban;
            if (kk < 10) {
                #pragma unroll
                for (int i = 0; i < 4; i++) bwn[i] = *(const bf16x8*)(pW + (size_t)i * 16 * XD + (kk + 1) * 32);
                ban = *(const bf16x8*)(pA + (kk + 1) * 32);
            }
            const int kc = kk * 32 + quad * 8;
            bf16x8 a[3];
            #pragma unroll
            for (int s2 = 0; s2 < 3; s2++) a[s2] = *(bf16x8*)&sX[(s2 * 16 + l15) * SX_STR + kc];
            #pragma unroll
            for (int i = 0; i < 4; i++)
                #pragma unroll
                for (int s2 = 0; s2 < 3; s2++)
                    acc[s2][i] = __builtin_amdgcn_mfma_f32_16x16x32_bf16(a[s2], bw[i], acc[s2][i], 0, 0, 0);
            #pragma unroll
            for (int s2 = 0; s2 < 3; s2++)
                accA[s2] = __builtin_amdgcn_mfma_f32_16x16x32_bf16(a[s2], ba, accA[s2], 0, 0, 0);
            if (kk < 10) {
                #pragma unroll
                for (int i = 0; i < 4; i++) bw[i] = bwn[i];
                ba = ban;
            }
        }
    }
    __syncthreads();   // all sX reads done before overlay writes

    // Phase 3: epilogue -> sH (overlay) and sA (overlay). FULL unroll is
    // load-bearing (rule #20): `unroll 1` here makes acc runtime-indexed ->
    // 48 floats spill to scratch (~530 MB/dispatch round-trip, R8/R9 bug).
    #pragma unroll
    for (int i = 0; i < 4; i++) {
        const int n = w * 64 + i * 16 + l15;
        const float bb = prm[PRM_B1 + n];
        #pragma unroll
        for (int s2 = 0; s2 < 3; s2++)
            #pragma unroll
            for (int r = 0; r < 4; r++)
                sH[(s2 * 16 + quad * 4 + r) * SH_STR + n] = (bf16)siluf(acc[s2][i][r] + bb);
    }
    {
        const int n = w * 16 + l15;
        const float ba1 = prm[PRM_AB1 + n];
        #pragma unroll
        for (int s2 = 0; s2 < 3; s2++)
            #pragma unroll
            for (int r = 0; r < 4; r++)
                sA[(s2 * 16 + quad * 4 + r) * SA_STR + n] = (bf16)siluf(accA[s2][r] + ba1);
    }
    __syncthreads();

    // Phase 4: scores = exp((silu(X@A1)@A2 + ab2)/8) -> plain global stream
    if (t < TE * NHEADS) {
        const int e = t >> 2, h = t & 3;
        if (e < ne) {
            float dot = 0.f;
            #pragma unroll
            for (int c = 0; c < 8; c++) {
                bf16x8 vv = *(bf16x8*)&sA[e * SA_STR + c * 8];
                #pragma unroll
                for (int ii = 0; ii < 8; ii++)
                    dot += (float)vv[ii] * sA2[(c * 8 + ii) * NHEADS + h];
            }
            scrS[(size_t)(e0 + e) * NHEADS + h] = __expf((dot + prm[PRM_AB2 + h]) * 0.125f);
        }
    }

    // Phase 5: GEMM2 H@W2T + b2 + edges0 -> new_edges (no pooled atomics)
    {
        f32x4 c2[3] = {z, z, z};
        const int n = w * 16 + l15;
        const bf16* pW2 = W2T + (size_t)n * H1D + quad * 8;
        bf16x8 b2f = *(const bf16x8*)pW2;
        #pragma unroll 1
        for (int kk = 0; kk < 8; kk++) {
            bf16x8 b2n;
            if (kk < 7) b2n = *(const bf16x8*)(pW2 + (kk + 1) * 32);
            const int kc = kk * 32 + quad * 8;
            #pragma unroll
            for (int s2 = 0; s2 < 3; s2++) {
                bf16x8 a = *(bf16x8*)&sH[(s2 * 16 + l15) * SH_STR + kc];
                c2[s2] = __builtin_amdgcn_mfma_f32_16x16x32_bf16(a, b2f, c2[s2], 0, 0, 0);
            }
            if (kk < 7) b2f = b2n;
        }
        const float bb2 = prm[PRM_B2 + n];
        #pragma unroll
        for (int s2 = 0; s2 < 3; s2++)
            #pragma unroll
            for (int r = 0; r < 4; r++) {
                const int row = s2 * 16 + quad * 4 + r;
                if (row < ne) {
                    size_t off = (size_t)(e0 + row) * EDIM + n;
                    float ev = isb ? (float)((const bf16*)edges0)[off] : ((const float*)edges0)[off];
                    float v = c2[s2][r] + bb2 + ev;
                    if (isb) ((bf16*)outNE)[off] = (bf16)v;
                    else     ((float*)outNE)[off] = v;
                }
            }
    }

    // Tail: bucket scatter for k_pool, moved here from k_prep's 1024-block pass.
    // Fire-and-forget (no barrier follows; kernel-boundary ordering makes it
    // visible to k_pool). sBi/sRi live in the never-overlaid IDX region.
    if (t < ne) {
        int seg = sBi[t] * NNODE + sRi[t];
        u32 pos = atomicAdd(&cnt[seg], 1u);
        if (pos < CAP) order[(size_t)seg * CAP + pos] = (u32)(e0 + t);
    }
}

// ---------------- K_pool: gather-based segment softmax-pool ----------------
__global__ __launch_bounds__(256) void k_pool(const u32* __restrict__ cnt,
                                              const u32* __restrict__ order,
                                              const float* __restrict__ scrS,
                                              const void* __restrict__ nodes,
                                              void* __restrict__ d_out) {
    const int t = threadIdx.x;
    const bool isb = probe_bf16(nodes, t);
    const int ws = blockIdx.x * 4 + (t >> 6);    // segment id, 0..4095
    const int lane = t & 63, h = lane >> 4;
    const void* newE = d_out;

    const u32 n1 = min(cnt[ws], (u32)CAP);
    const u32 base = (u32)ws * CAP;
    float acc = 0.f, dsum = 0.f;
    u32 i = 0;
    for (; i + 4 <= n1; i += 4) {                // 4-deep to keep loads in flight
        u32 ea = order[base + i], eb = order[base + i + 1];
        u32 ec = order[base + i + 2], ed = order[base + i + 3];
        float sa = scrS[(size_t)ea * NHEADS + h];
        float sb = scrS[(size_t)eb * NHEADS + h];
        float sc = scrS[(size_t)ec * NHEADS + h];
        float sd = scrS[(size_t)ed * NHEADS + h];
        float va = ldf(newE, (size_t)ea * EDIM + lane, isb);
        float vb = ldf(newE, (size_t)eb * EDIM + lane, isb);
        float vc = ldf(newE, (size_t)ec * EDIM + lane, isb);
        float vd = ldf(newE, (size_t)ed * EDIM + lane, isb);
        acc += va * sa + vb * sb + vc * sc + vd * sd;
        dsum += sa + sb + sc + sd;
    }
    for (; i < n1; i++) {
        u32 e = order[base + i];
        float s = scrS[(size_t)e * NHEADS + h];
        acc += ldf(newE, (size_t)e * EDIM + lane, isb) * s;
        dsum += s;
    }
    float r = (dsum > 0.f) ? acc / dsum : 0.f;
    size_t po = (size_t)E_TOT * OUTD + (size_t)ws * OUTD + lane;
    if (isb) ((bf16*)d_out)[po] = (bf16)r;
    else     ((float*)d_out)[po] = r;
}

static char* align_up(char* p, size_t a) {
    return (char*)(((uintptr_t)p + (a - 1)) & ~(uintptr_t)(a - 1));
}

extern "C" void kernel_launch(void* const* d_in, const int* in_sizes, int n_in,
                              void* d_out, int out_size, void* d_ws, size_t ws_size,
                              hipStream_t stream) {
    const void* nodes  = d_in[0];
    const void* edges0 = d_in[1];
    const void* globs  = d_in[2];
    const void* ln_g   = d_in[3];
    const void* ln_b   = d_in[4];
    const void* W1     = d_in[5];
    const void* b1     = d_in[6];
    const void* W2     = d_in[7];
    const void* b2     = d_in[8];
    const void* A1     = d_in[9];
    const void* ab1    = d_in[10];
    const void* A2     = d_in[11];
    const void* ab2    = d_in[12];
    const int*  bidx   = (const int*)d_in[13];
    const int*  sidx   = (const int*)d_in[14];
    const int*  ridx   = (const int*)d_in[15];

    char* p = (char*)d_ws;
    float* prm    = (float*)p;  p = align_up(p + PRM_TOT * 4, 256);
    bf16*  W1T    = (bf16*)p;   p = align_up(p + XD * H1D * 2, 256);
    bf16*  W2T    = (bf16*)p;   p = align_up(p + H1D * OUTD * 2, 256);
    bf16*  A1T    = (bf16*)p;   p = align_up(p + XD * AHD * 2, 256);
    u32*   cnt    = (u32*)p;    p += NSEG * 4;                      // 16 KB (zeroed by k_prep)
    u32*   order  = (u32*)p;    p += (size_t)NSEG * CAP * 4;        // 3 MB
    float* scrS   = (float*)p;  p += (size_t)E_TOT * NHEADS * 4;    // 4 MB

    k_prep<<<dim3(KP_NBLK), dim3(256), 0, stream>>>(
        nodes, W1, W2, A1, ln_g, ln_b, b1, b2, A2, ab1, ab2,
        W1T, W2T, A1T, prm, cnt);
    k_edge<<<dim3((E_TOT + TE - 1) / TE), dim3(256), 0, stream>>>(
        nodes, edges0, globs, prm,
        bidx, sidx, ridx, W1T, W2T, A1T, d_out, scrS, cnt, order);
    k_pool<<<dim3(NSEG / 4), dim3(256), 0, stream>>>(cnt, order, scrS, nodes, d_out);
}